// Round 16
// baseline (2418.888 us; speedup 1.0000x reference)
//
#include <hip/hip_runtime.h>

#define CINCH 512
#define ICH 256
#define NP 4096
#define BB 4
#define GSTRIDE ((size_t)NP*16)   // 65536: bytes per 16-row fragment group (u8 frag)

typedef __attribute__((ext_vector_type(8))) short bf16x8;
typedef __attribute__((ext_vector_type(8))) unsigned short u16x8;
typedef __attribute__((ext_vector_type(4))) float f32x4;
typedef __attribute__((ext_vector_type(4))) int i32x4;
typedef unsigned short u16;
typedef unsigned char u8;
typedef unsigned long long u64;

__device__ __forceinline__ u16 f2bf(float f){
  unsigned u = __builtin_bit_cast(unsigned, f);
  u += 0x7FFFu + ((u>>16)&1u);
  return (u16)(u>>16);
}

__device__ __forceinline__ float b0_thr(float dv){
  if (dv <= 0.f) return -3.4e38f;
  if (dv >= 1.f) return  3.4e38f;
  return (float)log((double)dv/(1.0-(double)dv));
}

// u8 frag-major byte address: [row/16][k/16][row%16][k%16]
__device__ __forceinline__ size_t fragaddr(int row, int k){
  return (size_t)(row>>4)*GSTRIDE + (size_t)(k>>4)*256 + (size_t)((row&15)*16 + (k&15));
}
// generic frag-major ELEMENT offset: [row/16][col/16][row%16][col%16]
__device__ __forceinline__ size_t fragidx(int row, int col){
  return ((size_t)(row>>4)*(NP>>4) + (size_t)(col>>4))*256 + (size_t)((row&15)*16 + (col&15));
}
// ndT bf16 frag-major u16 offset: [ic/16][n/32][ic%16][(n>>3)&3][n&7]
__device__ __forceinline__ size_t ndfrag(int ic, int n){
  return ((size_t)(ic>>4)*(NP>>5) + (size_t)(n>>5))*512
       + (size_t)((ic&15)*32 + ((n>>3)&3)*8 + (n&7));
}

// ---------------- K1: wfeat (bn1, fp32-chunk + fp64 fold) + nodes frag-bf16 ----------------
__global__ __launch_bounds__(256) void k_proj(const float* __restrict__ x,
    const float* __restrict__ w1w, const float* __restrict__ w1b,
    const float* __restrict__ g1, const float* __restrict__ be1,
    const float* __restrict__ mu1, const float* __restrict__ va1,
    const float* __restrict__ nw, const float* __restrict__ nb,
    float* __restrict__ Wt, u16* __restrict__ ndT){
  const int b = blockIdx.z;
  const int n0 = blockIdx.x*64, c0 = blockIdx.y*64;
  const int t = threadIdx.x, tx=t&15, ty=t>>4;
  __shared__ float as_[32][68];
  __shared__ float w1T[32][68];
  __shared__ float w2T[32][68];
  double acc1d[4][4];
  float acc1[4][4], acc2[4][4];
  #pragma unroll
  for(int i=0;i<4;i++)
    #pragma unroll
    for(int j=0;j<4;j++){acc1d[i][j]=0.0; acc1[i][j]=0.f; acc2[i][j]=0.f;}
  const float* xb = x + (size_t)b*CINCH*NP;
  for(int cb=0; cb<CINCH; cb+=32){
    __syncthreads();
    #pragma unroll
    for(int h=0;h<2;h++){
      int f = t + h*256;
      {
        int row=f>>4, c4=f&15;
        float4 v=*(const float4*)(xb + (size_t)(cb+row)*NP + n0 + c4*4);
        *(float4*)&as_[row][c4*4] = v;
      }
      {
        int k=f&31, ocq=f>>5;
        float l1[4], l2[4];
        #pragma unroll
        for(int r=0;r<4;r++){
          l1[r]=w1w[(size_t)(c0+ocq*4+r)*CINCH + cb + k];
          l2[r]=nw [(size_t)(c0+ocq*4+r)*CINCH + cb + k];
        }
        *(float4*)&w1T[k][ocq*4] = *(float4*)l1;
        *(float4*)&w2T[k][ocq*4] = *(float4*)l2;
      }
    }
    __syncthreads();
    #pragma unroll
    for(int k=0;k<32;k++){
      float4 av=*(const float4*)&as_[k][ty*4];
      float4 b1=*(const float4*)&w1T[k][tx*4];
      float4 b2=*(const float4*)&w2T[k][tx*4];
      float avf[4]={av.x,av.y,av.z,av.w};
      float b1f[4]={b1.x,b1.y,b1.z,b1.w};
      float b2f[4]={b2.x,b2.y,b2.z,b2.w};
      #pragma unroll
      for(int i=0;i<4;i++)
        #pragma unroll
        for(int j=0;j<4;j++){
          acc1[i][j] = fmaf(avf[i], b1f[j], acc1[i][j]);
          acc2[i][j] = fmaf(avf[i], b2f[j], acc2[i][j]);
        }
    }
    #pragma unroll
    for(int i=0;i<4;i++)
      #pragma unroll
      for(int j=0;j<4;j++){ acc1d[i][j] += (double)acc1[i][j]; acc1[i][j]=0.f; }
  }
  float inv[4], add[4], b1v[4], b2v[4];
  #pragma unroll
  for(int j=0;j<4;j++){
    int c=c0+tx*4+j;
    inv[j]=g1[c]*rsqrtf(va1[c]+1e-5f);
    add[j]=be1[c]-mu1[c]*inv[j];
    b1v[j]=w1b[c]; b2v[j]=nb[c];
  }
  #pragma unroll
  for(int i=0;i<4;i++){
    int n=n0+ty*4+i;
    float4 ov;
    float o[4];
    #pragma unroll
    for(int j=0;j<4;j++) o[j]=((float)(acc1d[i][j]+(double)b1v[j]))*inv[j]+add[j];
    ov.x=o[0];ov.y=o[1];ov.z=o[2];ov.w=o[3];
    *(float4*)(Wt + ((size_t)b*NP + n)*ICH + c0+tx*4) = ov;
  }
  u16* ndTb = ndT + (size_t)b*ICH*NP;
  #pragma unroll
  for(int j=0;j<4;j++){
    int ic=c0+tx*4+j;
    ushort4 uv;
    uv.x=f2bf(acc2[0][j]+b2v[j]); uv.y=f2bf(acc2[1][j]+b2v[j]);
    uv.z=f2bf(acc2[2][j]+b2v[j]); uv.w=f2bf(acc2[3][j]+b2v[j]);
    *(ushort4*)(ndTb + ndfrag(ic, n0+ty*4)) = uv;
  }
}

// ---------------- K2: iw (f32 frag) = Wt Wt^T/16 (fp32-chunk + fp64 fold) + b0 ----------------
__global__ __launch_bounds__(256) void k_iw(const float* __restrict__ Wb,
    float* __restrict__ ob, u8* __restrict__ b0f, const float* __restrict__ delta){
  int tt = blockIdx.x;
  tt = (tt&7)*260 + (tt>>3);                // XCD-bijective (2080%8==0)
  int bi = (int)((sqrtf(8.f*(float)tt+1.f)-1.f)*0.5f);
  while(bi*(bi+1)/2 > tt) bi--;
  while((bi+1)*(bi+2)/2 <= tt) bi++;
  int bj = tt - bi*(bi+1)/2;
  const int r0=bi*64, c0=bj*64;
  const float thr = b0_thr(delta[0]);
  __shared__ float asT[32][68], bsT[32][68];
  const int t=threadIdx.x, tx=t&15, ty=t>>4;
  double accd[4][4];
  float accf[4][4];
  #pragma unroll
  for(int i=0;i<4;i++)
    #pragma unroll
    for(int j=0;j<4;j++){accd[i][j]=0.0; accf[i][j]=0.f;}
  for(int k0=0;k0<ICH;k0+=32){
    __syncthreads();
    {
      int r=t>>3, kv=(t&7)*4;
      #pragma unroll
      for(int rr=r; rr<64; rr+=32){
        float4 va=*(const float4*)(Wb + (size_t)(r0+rr)*ICH + k0+kv);
        asT[kv+0][rr]=va.x; asT[kv+1][rr]=va.y; asT[kv+2][rr]=va.z; asT[kv+3][rr]=va.w;
        float4 vb=*(const float4*)(Wb + (size_t)(c0+rr)*ICH + k0+kv);
        bsT[kv+0][rr]=vb.x; bsT[kv+1][rr]=vb.y; bsT[kv+2][rr]=vb.z; bsT[kv+3][rr]=vb.w;
      }
    }
    __syncthreads();
    #pragma unroll
    for(int k=0;k<32;k++){
      float4 av=*(const float4*)&asT[k][ty*4];
      float4 bv=*(const float4*)&bsT[k][tx*4];
      float avf[4]={av.x,av.y,av.z,av.w};
      float bvf[4]={bv.x,bv.y,bv.z,bv.w};
      #pragma unroll
      for(int i=0;i<4;i++)
        #pragma unroll
        for(int j=0;j<4;j++)
          accf[i][j] = fmaf(avf[i], bvf[j], accf[i][j]);
    }
    #pragma unroll
    for(int i=0;i<4;i++)
      #pragma unroll
      for(int j=0;j<4;j++){ accd[i][j] += (double)accf[i][j]; accf[i][j]=0.f; }
  }
  float vv[4][4];
  char bvs[4][4];
  #pragma unroll
  for(int i=0;i<4;i++)
    #pragma unroll
    for(int j=0;j<4;j++){
      float v = (float)(accd[i][j]*0.0625);
      vv[i][j]=v;
      bvs[i][j]= v>=thr ? 1 : 0;
    }
  #pragma unroll
  for(int i=0;i<4;i++){
    float4 ov; ov.x=vv[i][0];ov.y=vv[i][1];ov.z=vv[i][2];ov.w=vv[i][3];
    *(float4*)(ob + fragidx(r0+ty*4+i, c0+tx*4)) = ov;
    unsigned w = (u8)bvs[i][0] | ((u8)bvs[i][1]<<8) | ((u8)bvs[i][2]<<16) | ((u8)bvs[i][3]<<24);
    *(unsigned*)(b0f + fragaddr(r0+ty*4+i, c0+tx*4)) = w;
  }
  if(bi!=bj){
    #pragma unroll
    for(int j=0;j<4;j++){
      float4 ov; ov.x=vv[0][j];ov.y=vv[1][j];ov.z=vv[2][j];ov.w=vv[3][j];
      *(float4*)(ob + fragidx(c0+tx*4+j, r0+ty*4)) = ov;
      unsigned w = (u8)bvs[0][j] | ((u8)bvs[1][j]<<8) | ((u8)bvs[2][j]<<16) | ((u8)bvs[3][j]<<24);
      *(unsigned*)(b0f + fragaddr(c0+tx*4+j, r0+ty*4)) = w;
    }
  }
}

// ---------------- K4: bh1 = b0 @ b0 (i8 MFMA, triangular, frag-layout in/out) ----------------
__global__ __launch_bounds__(256) void k_nn0(const u8* __restrict__ b0f,
    u8* __restrict__ bh1lo, u8* __restrict__ bh1hi){
  int tt = blockIdx.x;
  tt = (tt&7)*66 + (tt>>3);                 // XCD-bijective (528%8==0)
  int bi = (int)((sqrtf(8.f*(float)tt+1.f)-1.f)*0.5f);
  while(bi*(bi+1)/2 > tt) bi--;
  while((bi+1)*(bi+2)/2 <= tt) bi++;
  int bj = tt - bi*(bi+1)/2;
  const int r0=bi*128, c0=bj*128;
  const int t=threadIdx.x, w=t>>6, l=t&63;
  const int wr=(w>>1)*64, wc=(w&1)*64, fr=l&15, fg=l>>4;
  const i32x4 zer={0,0,0,0};
  i32x4 acc[4][4];
  #pragma unroll
  for(int i=0;i<4;i++)
    #pragma unroll
    for(int j=0;j<4;j++) acc[i][j]=zer;
  const size_t aoff = (size_t)fr*16 + (size_t)fg*256;
  const u8* pA[4]; const u8* pB[4];
  #pragma unroll
  for(int mi=0;mi<4;mi++) pA[mi]=b0f + (size_t)(((r0+wr)>>4) + mi)*GSTRIDE + aoff;
  #pragma unroll
  for(int nj=0;nj<4;nj++) pB[nj]=b0f + (size_t)(((c0+wc)>>4) + nj)*GSTRIDE + aoff;
  for(int k0=0;k0<NP;k0+=64){
    const size_t idx=(size_t)k0*16;
    i32x4 af[4], bf_[4];
    #pragma unroll
    for(int mi=0;mi<4;mi++) af[mi]=*(const i32x4*)(pA[mi]+idx);
    #pragma unroll
    for(int nj=0;nj<4;nj++) bf_[nj]=*(const i32x4*)(pB[nj]+idx);
    #pragma unroll
    for(int mi=0;mi<4;mi++)
      #pragma unroll
      for(int nj=0;nj<4;nj++)
        acc[mi][nj]=__builtin_amdgcn_mfma_i32_16x16x64_i8(af[mi],bf_[nj],acc[mi][nj],0,0,0);
  }
  #pragma unroll
  for(int mi=0;mi<4;mi++){
    #pragma unroll
    for(int nj=0;nj<4;nj++){
      int gc=c0+wc+nj*16+fr;
      int grb=r0+wr+mi*16+fg*4;
      u8 lob[4], hib[4];
      #pragma unroll
      for(int r=0;r<4;r++){
        int v=acc[mi][nj][r];
        lob[r]=(u8)(v&127); hib[r]=(u8)(v>>7);
        size_t ad=fragaddr(grb+r,gc);
        bh1lo[ad]=lob[r];
        bh1hi[ad]=hib[r];
      }
      if(bi!=bj){
        unsigned wlo = (unsigned)lob[0] | ((unsigned)lob[1]<<8) | ((unsigned)lob[2]<<16) | ((unsigned)lob[3]<<24);
        unsigned whi = (unsigned)hib[0] | ((unsigned)hib[1]<<8) | ((unsigned)hib[2]<<16) | ((unsigned)hib[3]<<24);
        size_t ad=fragaddr(gc,grb);
        *(unsigned*)(bh1lo+ad)=wlo;
        *(unsigned*)(bh1hi+ad)=whi;
      }
    }
  }
}

// ---------------- K5: bh2 (u16 lo + u8 hi frag) = bh1 @ b0 ----------------
// 128x128 triangular, LDS-staged panels (dedup wave requests, B read once), dual acc.
__global__ __launch_bounds__(256) void k_nn1(const u8* __restrict__ bh1lo,
    const u8* __restrict__ bh1hi, const u8* __restrict__ b0f,
    u16* __restrict__ bh2lo, u8* __restrict__ bh2hi){
  int tt = blockIdx.x;
  tt = (tt&7)*66 + (tt>>3);                 // XCD-bijective (528%8==0)
  int bi = (int)((sqrtf(8.f*(float)tt+1.f)-1.f)*0.5f);
  while(bi*(bi+1)/2 > tt) bi--;
  while((bi+1)*(bi+2)/2 <= tt) bi++;
  int bj = tt - bi*(bi+1)/2;
  const int r0=bi*128, c0=bj*128;
  const int t=threadIdx.x, w=t>>6, l=t&63;
  const int wr=(w>>1)*64, wc=(w&1)*64, fr=l&15, fg=l>>4;
  __shared__ __align__(16) u8 sAlo[8192];
  __shared__ __align__(16) u8 sAhi[8192];
  __shared__ __align__(16) u8 sB[8192];
  const i32x4 zer={0,0,0,0};
  i32x4 accl[4][4], acch[4][4];
  #pragma unroll
  for(int i=0;i<4;i++)
    #pragma unroll
    for(int j=0;j<4;j++){accl[i][j]=zer; acch[i][j]=zer;}
  const int rg=t>>5; const int gb=(t&31)*32;
  const size_t gA = (size_t)((r0>>4)+rg)*GSTRIDE + gb;
  const size_t gB = (size_t)((c0>>4)+rg)*GSTRIDE + gb;
  const int lofs = fg*256 + fr*16;
  for(int k0=0;k0<NP;k0+=64){
    __syncthreads();
    const size_t ko=(size_t)(k0>>4)*256;
    *(float4*)&sAlo[rg*1024+gb]    = *(const float4*)(bh1lo+gA+ko);
    *(float4*)&sAlo[rg*1024+gb+16] = *(const float4*)(bh1lo+gA+ko+16);
    *(float4*)&sAhi[rg*1024+gb]    = *(const float4*)(bh1hi+gA+ko);
    *(float4*)&sAhi[rg*1024+gb+16] = *(const float4*)(bh1hi+gA+ko+16);
    *(float4*)&sB[rg*1024+gb]      = *(const float4*)(b0f+gB+ko);
    *(float4*)&sB[rg*1024+gb+16]   = *(const float4*)(b0f+gB+ko+16);
    __syncthreads();
    i32x4 al[4], ah[4], bf_[4];
    #pragma unroll
    for(int mi=0;mi<4;mi++){
      al[mi]=*(const i32x4*)&sAlo[((wr>>4)+mi)*1024+lofs];
      ah[mi]=*(const i32x4*)&sAhi[((wr>>4)+mi)*1024+lofs];
    }
    #pragma unroll
    for(int nj=0;nj<4;nj++) bf_[nj]=*(const i32x4*)&sB[((wc>>4)+nj)*1024+lofs];
    #pragma unroll
    for(int mi=0;mi<4;mi++)
      #pragma unroll
      for(int nj=0;nj<4;nj++){
        accl[mi][nj]=__builtin_amdgcn_mfma_i32_16x16x64_i8(al[mi],bf_[nj],accl[mi][nj],0,0,0);
        acch[mi][nj]=__builtin_amdgcn_mfma_i32_16x16x64_i8(ah[mi],bf_[nj],acch[mi][nj],0,0,0);
      }
  }
  #pragma unroll
  for(int mi=0;mi<4;mi++){
    #pragma unroll
    for(int nj=0;nj<4;nj++){
      int gr=r0+wr+mi*16+fg*4, gc=c0+wc+nj*16+fr;
      u16 ml[4]; u8 mh[4];
      #pragma unroll
      for(int r=0;r<4;r++){
        int v = accl[mi][nj][r] + (acch[mi][nj][r]<<7);
        u16 lo=(u16)(v & 0xFFFF); u8 hi=(u8)(v>>16);
        ml[r]=lo; mh[r]=hi;
        size_t ad = fragidx(gr+r, gc);
        bh2lo[ad]=lo; bh2hi[ad]=hi;
      }
      if(bi!=bj){
        size_t ad = fragidx(gc, gr);
        *(ushort4*)(bh2lo + ad) = *(ushort4*)ml;
        *(unsigned*)(bh2hi + ad) = (unsigned)mh[0] | ((unsigned)mh[1]<<8)
                                 | ((unsigned)mh[2]<<16) | ((unsigned)mh[3]<<24);
      }
    }
  }
}

// ---------------- K6: fused flash-style softmax @ nodes (all frag-major inputs) ----------------
template<int H>
__device__ __forceinline__ void pv_body(const float* __restrict__ iw,
    const u8* __restrict__ bh1lo, const u8* __restrict__ bh1hi,
    const u16* __restrict__ bh2lo, const u8* __restrict__ bh2hi,
    const u16* __restrict__ ndT, const float* __restrict__ delta,
    float* __restrict__ traw, int rs,
    float (*Lm)[16], float (*Ls)[16], float (*Lacc)[16][4][64]){
  const int t = threadIdx.x, w = t>>6, l = t&63, fr = l&15, fg = l>>4;
  const int kbase = w*1024;                  // per-wave K quarter
  const float thr = b0_thr(delta[0]);
  const f32x4 zer={0.f,0.f,0.f,0.f};
  f32x4 acc[16];
  #pragma unroll
  for(int i=0;i<16;i++) acc[i]=zer;
  float m_run=-3.0e38f, s_run=0.f;
  const size_t af32 = ((size_t)rs*(NP>>4) + (size_t)(kbase>>4) + (fg>>1))*256
                    + (size_t)(fr*16 + (fg&1)*8);
  const float* ipf = iw + af32;
  const u16* p2lo = bh2lo + af32;
  const u8*  p2hi = bh2hi + af32;
  const u8* plo = bh1lo + af32;
  const u8* phi = bh1hi + af32;
  const size_t nb0 = (size_t)(kbase>>5)*512 + (size_t)(fr*32 + fg*8);
  for(int k0=0;k0<1024;k0+=32){
    const size_t idxf = (size_t)(k0>>4)*256;
    const size_t idxn = (size_t)k0*16;
    bf16x8 bfr[16];
    #pragma unroll
    for(int nj=0;nj<16;nj++)
      bfr[nj]=*(const bf16x8*)(ndT + (size_t)nj*65536 + nb0 + idxn);
    float vv[8];
    {
      float4 v0=*(const float4*)(ipf+idxf), v1=*(const float4*)(ipf+idxf+4);
      vv[0]=v0.x; vv[1]=v0.y; vv[2]=v0.z; vv[3]=v0.w;
      vv[4]=v1.x; vv[5]=v1.y; vv[6]=v1.z; vv[7]=v1.w;
    }
    float lg[8];
    if(H==0){
      #pragma unroll
      for(int e=0;e<8;e++) lg[e]=vv[e]>=thr?vv[e]:0.f;
    } else if(H==1){
      u64 llo=*(const u64*)(plo + idxf);
      u64 lhi=*(const u64*)(phi + idxf);
      #pragma unroll
      for(int e=0;e<8;e++){
        int bh_ = (int)((llo>>(8*e))&255u) | ((int)((lhi>>(8*e))&255u)<<7);
        lg[e]=(float)bh_*vv[e];
      }
    } else {
      u16x8 lv=*(const u16x8*)(p2lo + idxf);
      u64   hv=*(const u64*)(p2hi + idxf);
      #pragma unroll
      for(int e=0;e<8;e++){
        int v = (int)(unsigned short)lv[e] | ((int)((hv>>(8*e))&255u)<<16);
        lg[e]=(float)v*vv[e];
      }
    }
    float m_t = fmaxf(fmaxf(fmaxf(lg[0],lg[1]),fmaxf(lg[2],lg[3])),
                      fmaxf(fmaxf(lg[4],lg[5]),fmaxf(lg[6],lg[7])));
    m_t = fmaxf(m_t, __shfl_xor(m_t,16));
    m_t = fmaxf(m_t, __shfl_xor(m_t,32));
    if(__any(m_t > m_run + 6.0f)){
      float m_new = fmaxf(m_run, m_t);
      float sc = __expf(m_run - m_new);
      s_run *= sc;
      #pragma unroll
      for(int r=0;r<4;r++){
        float scr = __shfl(sc, fg*4+r);
        #pragma unroll
        for(int nj=0;nj<16;nj++) acc[nj][r]*=scr;
      }
      m_run = m_new;
    }
    bf16x8 af; float ss=0.f;
    #pragma unroll
    for(int e=0;e<8;e++){
      float p=__expf(lg[e]-m_run); ss+=p;
      af[e]=(short)f2bf(p);
    }
    s_run += ss;
    #pragma unroll
    for(int nj=0;nj<16;nj++)
      acc[nj]=__builtin_amdgcn_mfma_f32_16x16x32_bf16(af,bfr[nj],acc[nj],0,0,0);
  }
  s_run += __shfl_xor(s_run,16);
  s_run += __shfl_xor(s_run,32);
  if(fg==0) Lm[w][fr]=m_run;
  __syncthreads();
  float f_c[4];
  #pragma unroll
  for(int r=0;r<4;r++){
    int rr=fg*4+r;
    float ms=fmaxf(fmaxf(Lm[0][rr],Lm[1][rr]),fmaxf(Lm[2][rr],Lm[3][rr]));
    f_c[r]=__expf(Lm[w][rr]-ms);
  }
  {
    float ms=fmaxf(fmaxf(Lm[0][fr],Lm[1][fr]),fmaxf(Lm[2][fr],Lm[3][fr]));
    float fs=__expf(Lm[w][fr]-ms);
    if(fg==0) Ls[w][fr]=s_run*fs;
  }
  #pragma unroll
  for(int nj=0;nj<16;nj++)
    #pragma unroll
    for(int r=0;r<4;r++) acc[nj][r]*=f_c[r];
  if(w==1||w==3){
    int Ri=(w==1)?0:1;
    #pragma unroll
    for(int nj=0;nj<16;nj++)
      #pragma unroll
      for(int r=0;r<4;r++) Lacc[Ri][nj][r][l]=acc[nj][r];
  }
  __syncthreads();
  if(w==0||w==2){
    int Ri=(w==0)?0:1;
    #pragma unroll
    for(int nj=0;nj<16;nj++)
      #pragma unroll
      for(int r=0;r<4;r++) acc[nj][r]+=Lacc[Ri][nj][r][l];
  }
  __syncthreads();
  if(w==2){
    #pragma unroll
    for(int nj=0;nj<16;nj++)
      #pragma unroll
      for(int r=0;r<4;r++) Lacc[0][nj][r][l]=acc[nj][r];
  }
  __syncthreads();
  if(w==0){
    float sst[4];
    #pragma unroll
    for(int r=0;r<4;r++){
      int rr=fg*4+r;
      sst[r]=1.0f/(Ls[0][rr]+Ls[1][rr]+Ls[2][rr]+Ls[3][rr]);
    }
    #pragma unroll
    for(int nj=0;nj<16;nj++)
      #pragma unroll
      for(int r=0;r<4;r++){
        float v=(acc[nj][r]+Lacc[0][nj][r][l])*sst[r];
        traw[(size_t)(rs*16+fg*4+r)*ICH + nj*16+fr]=v;
      }
  }
}

// grid = 768 (1D): work-id -> rs = idx/3, hop = idx%3; XCD-chunked swizzle
__global__ __launch_bounds__(256) void k_pv3(const float* __restrict__ iw,
    const u8* __restrict__ bh1lo, const u8* __restrict__ bh1hi,
    const u16* __restrict__ bh2lo, const u8* __restrict__ bh2hi,
    const u16* __restrict__ ndT, const float* __restrict__ delta,
    float* __restrict__ trawcat){
  __shared__ float Lm[4][16], Ls[4][16];
  __shared__ float Lacc[2][16][4][64];
  int idx = blockIdx.x;
  idx = (idx&7)*96 + (idx>>3);              // bijective (768 = 8*96)
  const int rs = idx/3, h = idx - rs*3;
  float* traw = trawcat + (size_t)h*NP*ICH;
  if(h==0)      pv_body<0>(iw,bh1lo,bh1hi,bh2lo,bh2hi,ndT,delta,traw,rs,Lm,Ls,Lacc);
  else if(h==1) pv_body<1>(iw,bh1lo,bh1hi,bh2lo,bh2hi,ndT,delta,traw,rs,Lm,Ls,Lacc);
  else          pv_body<2>(iw,bh1lo,bh1hi,bh2lo,bh2hi,ndT,delta,traw,rs,Lm,Ls,Lacc);
}

// ---------------- prep: fold hop/fuse/bnf into res GEMM ----------------
__global__ __launch_bounds__(256) void k_prepA(const float* __restrict__ fw,
    const float* __restrict__ hw, const float* __restrict__ hb,
    const float* __restrict__ fb,
    const float* __restrict__ gf, const float* __restrict__ bef,
    const float* __restrict__ muf, const float* __restrict__ vaf,
    float* __restrict__ G, float* __restrict__ cf,
    float* __restrict__ sf, float* __restrict__ tf){
  const int t=threadIdx.x;
  if(blockIdx.x<768){
    int i=blockIdx.x>>8, oc=blockIdx.x&255;
    float s=0.f;
    const float* fr_=fw + (size_t)oc*768 + i*256;
    const float* hp=hw + (size_t)i*ICH*ICH + t;
    for(int j=0;j<256;j++) s=fmaf(fr_[j], hp[(size_t)j*ICH], s);
    G[((size_t)i*ICH + oc)*ICH + t]=s;
  } else {
    float iv=gf[t]*rsqrtf(vaf[t]+1e-5f);
    sf[t]=iv;
    tf[t]=bef[t]-muf[t]*iv;
    float s=fb[t];
    const float* fr_=fw + (size_t)t*768;
    for(int k=0;k<768;k++) s=fmaf(fr_[k], hb[k], s);
    cf[t]=s;
  }
}

__global__ __launch_bounds__(256) void k_prepB(const float* __restrict__ rw,
    const float* __restrict__ rb, const float* __restrict__ G,
    const float* __restrict__ cf, const float* __restrict__ sf,
    const float* __restrict__ tf, float* __restrict__ Wcat,
    float* __restrict__ evec){
  const int oc=blockIdx.x, t=threadIdx.x;
  __shared__ float rs_[256], rw2_[256];
  rw2_[t]=rw[(size_t)oc*512 + 256 + t];
  rs_[t]=rw2_[t]*sf[t];
  __syncthreads();
  Wcat[(size_t)oc*1024 + t] = rw[(size_t)oc*512 + t];
  #pragma unroll
  for(int i=0;i<3;i++){
    float s=0.f;
    const float* gp=G + (size_t)i*ICH*ICH + t;
    for(int m=0;m<256;m++) s=fmaf(rs_[m], gp[(size_t)m*ICH], s);
    Wcat[(size_t)oc*1024 + 256 + i*256 + t]=s;
  }
  if(t==0){
    float s=rb[oc];
    for(int m=0;m<256;m++) s=fmaf(rs_[m],cf[m],s)+rw2_[m]*tf[m];
    evec[oc]=s;
  }
}

// ---------------- tail: out = bnr( R0@x256 + Wcat_hops@trawcat + e ), transposed LDS ----------------
__global__ __launch_bounds__(256) void k_tail2(const float* __restrict__ trawcat,
    const float* __restrict__ Wcat, const float* __restrict__ evec,
    const float* __restrict__ xsrc,
    const float* __restrict__ g, const float* __restrict__ be,
    const float* __restrict__ mu, const float* __restrict__ va,
    float* __restrict__ Cout){
  const int n0=blockIdx.x*64, c0=blockIdx.y*64;
  __shared__ float asT[32][68], bsT[32][68];
  const int t=threadIdx.x, tx=t&15, ty=t>>4;
  float acc[4][4];
  #pragma unroll
  for(int i=0;i<4;i++)
    #pragma unroll
    for(int j=0;j<4;j++) acc[i][j]=0.f;
  for(int k0=0;k0<1024;k0+=32){
    __syncthreads();
    if(k0<256){
      int kk=t>>4, nv=(t&15)*4;
      #pragma unroll
      for(int k2=kk;k2<32;k2+=16)
        *(float4*)&asT[k2][nv] = *(const float4*)(xsrc + (size_t)(k0+k2)*NP + n0+nv);
    } else {
      int hop=(k0-256)>>8, kk0=(k0-256)&255;
      const float* A=trawcat + (size_t)hop*NP*ICH;
      int r=t>>3, kv=(t&7)*4;
      #pragma unroll
      for(int rr=r;rr<64;rr+=32){
        float4 v=*(const float4*)(A + (size_t)(n0+rr)*ICH + kk0+kv);
        asT[kv+0][rr]=v.x; asT[kv+1][rr]=v.y; asT[kv+2][rr]=v.z; asT[kv+3][rr]=v.w;
      }
    }
    {
      int r=t>>3, kv=(t&7)*4;
      #pragma unroll
      for(int rr=r;rr<64;rr+=32){
        float4 v=*(const float4*)(Wcat + (size_t)(c0+rr)*1024 + k0+kv);
        bsT[kv+0][rr]=v.x; bsT[kv+1][rr]=v.y; bsT[kv+2][rr]=v.z; bsT[kv+3][rr]=v.w;
      }
    }
    __syncthreads();
    #pragma unroll
    for(int k=0;k<32;k++){
      float4 av=*(const float4*)&asT[k][ty*4];
      float4 bv=*(const float4*)&bsT[k][tx*4];
      float avf[4]={av.x,av.y,av.z,av.w};
      float bvf[4]={bv.x,bv.y,bv.z,bv.w};
      #pragma unroll
      for(int i=0;i<4;i++)
        #pragma unroll
        for(int j=0;j<4;j++) acc[i][j]+=avf[i]*bvf[j];
    }
  }
  const int col=c0+tx*4, row=n0+ty*4;
  float sc[4], ad[4];
  #pragma unroll
  for(int j=0;j<4;j++){
    int c=col+j;
    float iv=g[c]*rsqrtf(va[c]+1e-5f);
    sc[j]=iv; ad[j]=be[c]-mu[c]*iv + evec[c]*iv;
  }
  #pragma unroll
  for(int j=0;j<4;j++){
    float4 ov;
    ov.x=acc[0][j]*sc[j]+ad[j]; ov.y=acc[1][j]*sc[j]+ad[j];
    ov.z=acc[2][j]*sc[j]+ad[j]; ov.w=acc[3][j]*sc[j]+ad[j];
    *(float4*)(Cout + (size_t)(col+j)*NP + row) = ov;
  }
}

__global__ void k_diag(float* out, int n, float val){
  int i = blockIdx.x*256 + threadIdx.x;
  if(i<n) out[i] = (i==0)? val : 0.f;
}

extern "C" void kernel_launch(void* const* d_in, const int* in_sizes, int n_in,
                              void* d_out, int out_size, void* d_ws, size_t ws_size,
                              hipStream_t stream){
  const float* x    =(const float*)d_in[0];
  const float* delta=(const float*)d_in[1];
  const float* w1w  =(const float*)d_in[2];
  const float* w1b  =(const float*)d_in[3];
  const float* g1   =(const float*)d_in[4];
  const float* be1  =(const float*)d_in[5];
  const float* mu1  =(const float*)d_in[6];
  const float* va1  =(const float*)d_in[7];
  const float* nw   =(const float*)d_in[8];
  const float* nb   =(const float*)d_in[9];
  const float* hw   =(const float*)d_in[10];
  const float* hb   =(const float*)d_in[11];
  const float* fw   =(const float*)d_in[12];
  const float* fb   =(const float*)d_in[13];
  const float* gf   =(const float*)d_in[14];
  const float* bef  =(const float*)d_in[15];
  const float* muf  =(const float*)d_in[16];
  const float* vaf  =(const float*)d_in[17];
  const float* rw   =(const float*)d_in[18];
  const float* rb   =(const float*)d_in[19];
  const float* gr   =(const float*)d_in[20];
  const float* ber  =(const float*)d_in[21];
  const float* mur  =(const float*)d_in[22];
  const float* var_ =(const float*)d_in[23];
  float* out=(float*)d_out;

  char* ws=(char*)d_ws;
  size_t o=0;
  auto alloc=[&](size_t bytes)->char*{ char* p=ws+o; o+=(bytes+255)&~(size_t)255; return p; };
  const size_t NN=(size_t)NP*NP;
  float* Wt    =(float*)alloc((size_t)BB*NP*ICH*4);   // 16.8 MB
  u16*   ndT   =(u16*)  alloc((size_t)BB*ICH*NP*2);   // 8.4 MB (frag-major)
  float* iw    =(float*)alloc(NN*4);                  // 67.1 MB (f32 frag)
  u8*    b0f   =(u8*)   alloc(NN);                    // 16.8 MB (u8 frag)
  u8*    bh1lo =(u8*)   alloc(NN);                    // 16.8 MB (u8 frag)
  u8*    bh1hi =(u8*)   alloc(NN);                    // 16.8 MB (u8 frag)
  u16*   bh2lo =(u16*)  alloc(NN*2);                  // 33.6 MB (u16 frag)
  u8*    bh2hi =(u8*)   alloc(NN);                    // 16.8 MB (u8 frag)
  float* trawc =(float*)alloc((size_t)3*NP*ICH*4);    // 12.6 MB
  float* G     =(float*)alloc((size_t)3*ICH*ICH*4);
  float* Wcat  =(float*)alloc((size_t)CINCH*1024*4);
  float* evec  =(float*)alloc(CINCH*4);
  float* cf    =(float*)alloc(ICH*4);
  float* sf    =(float*)alloc(ICH*4);
  float* tf    =(float*)alloc(ICH*4);
  if(o > ws_size){
    k_diag<<<dim3((out_size+255)/256),dim3(256),0,stream>>>(out, out_size, (float)ws_size);
    return;
  }
  dim3 blk(256);
  k_prepA<<<dim3(769),blk,0,stream>>>(fw,hw,hb,fb,gf,bef,muf,vaf,G,cf,sf,tf);
  k_prepB<<<dim3(512),blk,0,stream>>>(rw,rb,G,cf,sf,tf,Wcat,evec);
  k_proj<<<dim3(NP/64,ICH/64,BB),blk,0,stream>>>(x,w1w,w1b,g1,be1,mu1,va1,nw,nb,Wt,ndT);
  for(int b=0;b<BB;b++){
    const float* Wt_b  = Wt + (size_t)b*NP*ICH;
    const u16*   ndT_b = ndT + (size_t)b*ICH*NP;
    const float* x_b   = x + (size_t)b*CINCH*NP;
    float*       out_b = out + (size_t)b*CINCH*NP;
    k_iw  <<<dim3(2080),blk,0,stream>>>(Wt_b,iw,b0f,delta);
    k_nn0 <<<dim3(528),blk,0,stream>>>(b0f,bh1lo,bh1hi);
    k_nn1 <<<dim3(528),blk,0,stream>>>(bh1lo,bh1hi,b0f,bh2lo,bh2hi);
    k_pv3 <<<dim3(768),blk,0,stream>>>(iw,bh1lo,bh1hi,bh2lo,bh2hi,ndT_b,delta,trawc);
    k_tail2<<<dim3(64,8),blk,0,stream>>>(trawc,Wcat,evec,x_b,gr,ber,mur,var_,out_b);
  }
}

// Round 17
// 2415.294 us; speedup vs baseline: 1.0015x; 1.0015x over previous
//
#include <hip/hip_runtime.h>

#define CINCH 512
#define ICH 256
#define NP 4096
#define BB 4
#define GSTRIDE ((size_t)NP*16)   // 65536: bytes per 16-row fragment group (u8 frag)

typedef __attribute__((ext_vector_type(8))) short bf16x8;
typedef __attribute__((ext_vector_type(8))) unsigned short u16x8;
typedef __attribute__((ext_vector_type(4))) float f32x4;
typedef __attribute__((ext_vector_type(4))) int i32x4;
typedef unsigned short u16;
typedef unsigned char u8;
typedef unsigned long long u64;

__device__ __forceinline__ u16 f2bf(float f){
  unsigned u = __builtin_bit_cast(unsigned, f);
  u += 0x7FFFu + ((u>>16)&1u);
  return (u16)(u>>16);
}

__device__ __forceinline__ float b0_thr(float dv){
  if (dv <= 0.f) return -3.4e38f;
  if (dv >= 1.f) return  3.4e38f;
  return (float)log((double)dv/(1.0-(double)dv));
}

// u8 frag-major byte address: [row/16][k/16][row%16][k%16]
__device__ __forceinline__ size_t fragaddr(int row, int k){
  return (size_t)(row>>4)*GSTRIDE + (size_t)(k>>4)*256 + (size_t)((row&15)*16 + (k&15));
}
// generic frag-major ELEMENT offset: [row/16][col/16][row%16][col%16]
__device__ __forceinline__ size_t fragidx(int row, int col){
  return ((size_t)(row>>4)*(NP>>4) + (size_t)(col>>4))*256 + (size_t)((row&15)*16 + (col&15));
}
// ndT bf16 frag-major u16 offset: [ic/16][n/32][ic%16][(n>>3)&3][n&7]
__device__ __forceinline__ size_t ndfrag(int ic, int n){
  return ((size_t)(ic>>4)*(NP>>5) + (size_t)(n>>5))*512
       + (size_t)((ic&15)*32 + ((n>>3)&3)*8 + (n&7));
}

// ---------------- K1: wfeat (bn1, fp32-chunk + fp64 fold) + nodes frag-bf16 ----------------
__global__ __launch_bounds__(256) void k_proj(const float* __restrict__ x,
    const float* __restrict__ w1w, const float* __restrict__ w1b,
    const float* __restrict__ g1, const float* __restrict__ be1,
    const float* __restrict__ mu1, const float* __restrict__ va1,
    const float* __restrict__ nw, const float* __restrict__ nb,
    float* __restrict__ Wt, u16* __restrict__ ndT){
  const int b = blockIdx.z;
  const int n0 = blockIdx.x*64, c0 = blockIdx.y*64;
  const int t = threadIdx.x, tx=t&15, ty=t>>4;
  __shared__ float as_[32][68];
  __shared__ float w1T[32][68];
  __shared__ float w2T[32][68];
  double acc1d[4][4];
  float acc1[4][4], acc2[4][4];
  #pragma unroll
  for(int i=0;i<4;i++)
    #pragma unroll
    for(int j=0;j<4;j++){acc1d[i][j]=0.0; acc1[i][j]=0.f; acc2[i][j]=0.f;}
  const float* xb = x + (size_t)b*CINCH*NP;
  for(int cb=0; cb<CINCH; cb+=32){
    __syncthreads();
    #pragma unroll
    for(int h=0;h<2;h++){
      int f = t + h*256;
      {
        int row=f>>4, c4=f&15;
        float4 v=*(const float4*)(xb + (size_t)(cb+row)*NP + n0 + c4*4);
        *(float4*)&as_[row][c4*4] = v;
      }
      {
        int k=f&31, ocq=f>>5;
        float l1[4], l2[4];
        #pragma unroll
        for(int r=0;r<4;r++){
          l1[r]=w1w[(size_t)(c0+ocq*4+r)*CINCH + cb + k];
          l2[r]=nw [(size_t)(c0+ocq*4+r)*CINCH + cb + k];
        }
        *(float4*)&w1T[k][ocq*4] = *(float4*)l1;
        *(float4*)&w2T[k][ocq*4] = *(float4*)l2;
      }
    }
    __syncthreads();
    #pragma unroll
    for(int k=0;k<32;k++){
      float4 av=*(const float4*)&as_[k][ty*4];
      float4 b1=*(const float4*)&w1T[k][tx*4];
      float4 b2=*(const float4*)&w2T[k][tx*4];
      float avf[4]={av.x,av.y,av.z,av.w};
      float b1f[4]={b1.x,b1.y,b1.z,b1.w};
      float b2f[4]={b2.x,b2.y,b2.z,b2.w};
      #pragma unroll
      for(int i=0;i<4;i++)
        #pragma unroll
        for(int j=0;j<4;j++){
          acc1[i][j] = fmaf(avf[i], b1f[j], acc1[i][j]);
          acc2[i][j] = fmaf(avf[i], b2f[j], acc2[i][j]);
        }
    }
    #pragma unroll
    for(int i=0;i<4;i++)
      #pragma unroll
      for(int j=0;j<4;j++){ acc1d[i][j] += (double)acc1[i][j]; acc1[i][j]=0.f; }
  }
  float inv[4], add[4], b1v[4], b2v[4];
  #pragma unroll
  for(int j=0;j<4;j++){
    int c=c0+tx*4+j;
    inv[j]=g1[c]*rsqrtf(va1[c]+1e-5f);
    add[j]=be1[c]-mu1[c]*inv[j];
    b1v[j]=w1b[c]; b2v[j]=nb[c];
  }
  #pragma unroll
  for(int i=0;i<4;i++){
    int n=n0+ty*4+i;
    float4 ov;
    float o[4];
    #pragma unroll
    for(int j=0;j<4;j++) o[j]=((float)(acc1d[i][j]+(double)b1v[j]))*inv[j]+add[j];
    ov.x=o[0];ov.y=o[1];ov.z=o[2];ov.w=o[3];
    *(float4*)(Wt + ((size_t)b*NP + n)*ICH + c0+tx*4) = ov;
  }
  u16* ndTb = ndT + (size_t)b*ICH*NP;
  #pragma unroll
  for(int j=0;j<4;j++){
    int ic=c0+tx*4+j;
    ushort4 uv;
    uv.x=f2bf(acc2[0][j]+b2v[j]); uv.y=f2bf(acc2[1][j]+b2v[j]);
    uv.z=f2bf(acc2[2][j]+b2v[j]); uv.w=f2bf(acc2[3][j]+b2v[j]);
    *(ushort4*)(ndTb + ndfrag(ic, n0+ty*4)) = uv;
  }
}

// ---------------- K2: iw (f32 frag) = Wt Wt^T/16 (fp32-chunk + fp64 fold) + b0 ----------------
__global__ __launch_bounds__(256) void k_iw(const float* __restrict__ Wb,
    float* __restrict__ ob, u8* __restrict__ b0f, const float* __restrict__ delta){
  int tt = blockIdx.x;
  tt = (tt&7)*260 + (tt>>3);                // XCD-bijective (2080%8==0)
  int bi = (int)((sqrtf(8.f*(float)tt+1.f)-1.f)*0.5f);
  while(bi*(bi+1)/2 > tt) bi--;
  while((bi+1)*(bi+2)/2 <= tt) bi++;
  int bj = tt - bi*(bi+1)/2;
  const int r0=bi*64, c0=bj*64;
  const float thr = b0_thr(delta[0]);
  __shared__ float asT[32][68], bsT[32][68];
  const int t=threadIdx.x, tx=t&15, ty=t>>4;
  double accd[4][4];
  float accf[4][4];
  #pragma unroll
  for(int i=0;i<4;i++)
    #pragma unroll
    for(int j=0;j<4;j++){accd[i][j]=0.0; accf[i][j]=0.f;}
  for(int k0=0;k0<ICH;k0+=32){
    __syncthreads();
    {
      int r=t>>3, kv=(t&7)*4;
      #pragma unroll
      for(int rr=r; rr<64; rr+=32){
        float4 va=*(const float4*)(Wb + (size_t)(r0+rr)*ICH + k0+kv);
        asT[kv+0][rr]=va.x; asT[kv+1][rr]=va.y; asT[kv+2][rr]=va.z; asT[kv+3][rr]=va.w;
        float4 vb=*(const float4*)(Wb + (size_t)(c0+rr)*ICH + k0+kv);
        bsT[kv+0][rr]=vb.x; bsT[kv+1][rr]=vb.y; bsT[kv+2][rr]=vb.z; bsT[kv+3][rr]=vb.w;
      }
    }
    __syncthreads();
    #pragma unroll
    for(int k=0;k<32;k++){
      float4 av=*(const float4*)&asT[k][ty*4];
      float4 bv=*(const float4*)&bsT[k][tx*4];
      float avf[4]={av.x,av.y,av.z,av.w};
      float bvf[4]={bv.x,bv.y,bv.z,bv.w};
      #pragma unroll
      for(int i=0;i<4;i++)
        #pragma unroll
        for(int j=0;j<4;j++)
          accf[i][j] = fmaf(avf[i], bvf[j], accf[i][j]);
    }
    #pragma unroll
    for(int i=0;i<4;i++)
      #pragma unroll
      for(int j=0;j<4;j++){ accd[i][j] += (double)accf[i][j]; accf[i][j]=0.f; }
  }
  float vv[4][4];
  char bvs[4][4];
  #pragma unroll
  for(int i=0;i<4;i++)
    #pragma unroll
    for(int j=0;j<4;j++){
      float v = (float)(accd[i][j]*0.0625);
      vv[i][j]=v;
      bvs[i][j]= v>=thr ? 1 : 0;
    }
  #pragma unroll
  for(int i=0;i<4;i++){
    float4 ov; ov.x=vv[i][0];ov.y=vv[i][1];ov.z=vv[i][2];ov.w=vv[i][3];
    *(float4*)(ob + fragidx(r0+ty*4+i, c0+tx*4)) = ov;
    unsigned w = (u8)bvs[i][0] | ((u8)bvs[i][1]<<8) | ((u8)bvs[i][2]<<16) | ((u8)bvs[i][3]<<24);
    *(unsigned*)(b0f + fragaddr(r0+ty*4+i, c0+tx*4)) = w;
  }
  if(bi!=bj){
    #pragma unroll
    for(int j=0;j<4;j++){
      float4 ov; ov.x=vv[0][j];ov.y=vv[1][j];ov.z=vv[2][j];ov.w=vv[3][j];
      *(float4*)(ob + fragidx(c0+tx*4+j, r0+ty*4)) = ov;
      unsigned w = (u8)bvs[0][j] | ((u8)bvs[1][j]<<8) | ((u8)bvs[2][j]<<16) | ((u8)bvs[3][j]<<24);
      *(unsigned*)(b0f + fragaddr(c0+tx*4+j, r0+ty*4)) = w;
    }
  }
}

// ---------------- K4: bh1 = b0 @ b0 (i8 MFMA, triangular, frag-layout in/out) ----------------
__global__ __launch_bounds__(256) void k_nn0(const u8* __restrict__ b0f,
    u8* __restrict__ bh1lo, u8* __restrict__ bh1hi){
  int tt = blockIdx.x;
  tt = (tt&7)*66 + (tt>>3);                 // XCD-bijective (528%8==0)
  int bi = (int)((sqrtf(8.f*(float)tt+1.f)-1.f)*0.5f);
  while(bi*(bi+1)/2 > tt) bi--;
  while((bi+1)*(bi+2)/2 <= tt) bi++;
  int bj = tt - bi*(bi+1)/2;
  const int r0=bi*128, c0=bj*128;
  const int t=threadIdx.x, w=t>>6, l=t&63;
  const int wr=(w>>1)*64, wc=(w&1)*64, fr=l&15, fg=l>>4;
  const i32x4 zer={0,0,0,0};
  i32x4 acc[4][4];
  #pragma unroll
  for(int i=0;i<4;i++)
    #pragma unroll
    for(int j=0;j<4;j++) acc[i][j]=zer;
  const size_t aoff = (size_t)fr*16 + (size_t)fg*256;
  const u8* pA[4]; const u8* pB[4];
  #pragma unroll
  for(int mi=0;mi<4;mi++) pA[mi]=b0f + (size_t)(((r0+wr)>>4) + mi)*GSTRIDE + aoff;
  #pragma unroll
  for(int nj=0;nj<4;nj++) pB[nj]=b0f + (size_t)(((c0+wc)>>4) + nj)*GSTRIDE + aoff;
  for(int k0=0;k0<NP;k0+=64){
    const size_t idx=(size_t)k0*16;
    i32x4 af[4], bf_[4];
    #pragma unroll
    for(int mi=0;mi<4;mi++) af[mi]=*(const i32x4*)(pA[mi]+idx);
    #pragma unroll
    for(int nj=0;nj<4;nj++) bf_[nj]=*(const i32x4*)(pB[nj]+idx);
    #pragma unroll
    for(int mi=0;mi<4;mi++)
      #pragma unroll
      for(int nj=0;nj<4;nj++)
        acc[mi][nj]=__builtin_amdgcn_mfma_i32_16x16x64_i8(af[mi],bf_[nj],acc[mi][nj],0,0,0);
  }
  #pragma unroll
  for(int mi=0;mi<4;mi++){
    #pragma unroll
    for(int nj=0;nj<4;nj++){
      int gc=c0+wc+nj*16+fr;
      int grb=r0+wr+mi*16+fg*4;
      u8 lob[4], hib[4];
      #pragma unroll
      for(int r=0;r<4;r++){
        int v=acc[mi][nj][r];
        lob[r]=(u8)(v&127); hib[r]=(u8)(v>>7);
        size_t ad=fragaddr(grb+r,gc);
        bh1lo[ad]=lob[r];
        bh1hi[ad]=hib[r];
      }
      if(bi!=bj){
        unsigned wlo = (unsigned)lob[0] | ((unsigned)lob[1]<<8) | ((unsigned)lob[2]<<16) | ((unsigned)lob[3]<<24);
        unsigned whi = (unsigned)hib[0] | ((unsigned)hib[1]<<8) | ((unsigned)hib[2]<<16) | ((unsigned)hib[3]<<24);
        size_t ad=fragaddr(gc,grb);
        *(unsigned*)(bh1lo+ad)=wlo;
        *(unsigned*)(bh1hi+ad)=whi;
      }
    }
  }
}

// ---------------- K5a: bh2 pairs — 128x256 tiles, two-sweep single acc ----------------
// 256 blocks; row tile bi (128 rows), col range p*256..p*256+255 (within lower triangle).
__global__ __launch_bounds__(256) void k_nn1p(const u8* __restrict__ bh1lo,
    const u8* __restrict__ bh1hi, const u8* __restrict__ b0f,
    u16* __restrict__ bh2lo, u8* __restrict__ bh2hi){
  int idx = blockIdx.x;
  idx = (idx&7)*32 + (idx>>3);              // XCD-bijective (256 = 8*32)
  // cum(b) = number of pair-blocks in rows < b: (b*b - (b&1))/4
  int bi = (int)(2.f*sqrtf((float)idx)) + 1;
  if(bi>32) bi=32;
  while(((bi*bi-(bi&1))>>2) > idx) bi--;
  while((((bi+1)*(bi+1)-((bi+1)&1))>>2) <= idx) bi++;
  const int p = idx - ((bi*bi-(bi&1))>>2);
  const int r0 = bi*128, c0 = p*256;
  const int t=threadIdx.x, w=t>>6, l=t&63;
  const int wr=(w>>1)*64, wc=(w&1)*128, fr=l&15, fg=l>>4;
  const i32x4 zer={0,0,0,0};
  i32x4 acc[4][8];
  #pragma unroll
  for(int i=0;i<4;i++)
    #pragma unroll
    for(int j=0;j<8;j++) acc[i][j]=zer;
  const size_t aoff = (size_t)fr*16 + (size_t)fg*256;
  const size_t gAlo = (size_t)((r0+wr)>>4)*GSTRIDE + aoff;
  const size_t gB   = (size_t)((c0+wc)>>4)*GSTRIDE + aoff;
  // hi sweep
  for(int k0=0;k0<NP;k0+=64){
    const size_t kk=(size_t)k0*16;
    i32x4 ah[4], bf_[8];
    #pragma unroll
    for(int mi=0;mi<4;mi++) ah[mi]=*(const i32x4*)(bh1hi + gAlo + (size_t)mi*GSTRIDE + kk);
    #pragma unroll
    for(int nj=0;nj<8;nj++) bf_[nj]=*(const i32x4*)(b0f + gB + (size_t)nj*GSTRIDE + kk);
    #pragma unroll
    for(int mi=0;mi<4;mi++)
      #pragma unroll
      for(int nj=0;nj<8;nj++)
        acc[mi][nj]=__builtin_amdgcn_mfma_i32_16x16x64_i8(ah[mi],bf_[nj],acc[mi][nj],0,0,0);
  }
  #pragma unroll
  for(int mi=0;mi<4;mi++)
    #pragma unroll
    for(int nj=0;nj<8;nj++)
      #pragma unroll
      for(int r=0;r<4;r++) acc[mi][nj][r] <<= 7;
  // lo sweep
  for(int k0=0;k0<NP;k0+=64){
    const size_t kk=(size_t)k0*16;
    i32x4 al[4], bf_[8];
    #pragma unroll
    for(int mi=0;mi<4;mi++) al[mi]=*(const i32x4*)(bh1lo + gAlo + (size_t)mi*GSTRIDE + kk);
    #pragma unroll
    for(int nj=0;nj<8;nj++) bf_[nj]=*(const i32x4*)(b0f + gB + (size_t)nj*GSTRIDE + kk);
    #pragma unroll
    for(int mi=0;mi<4;mi++)
      #pragma unroll
      for(int nj=0;nj<8;nj++)
        acc[mi][nj]=__builtin_amdgcn_mfma_i32_16x16x64_i8(al[mi],bf_[nj],acc[mi][nj],0,0,0);
  }
  #pragma unroll
  for(int mi=0;mi<4;mi++){
    #pragma unroll
    for(int nj=0;nj<8;nj++){
      int gr=r0+wr+mi*16+fg*4, gc=c0+wc+nj*16+fr;
      u16 ml[4]; u8 mh[4];
      #pragma unroll
      for(int r=0;r<4;r++){
        int v = acc[mi][nj][r];
        u16 lo=(u16)(v & 0xFFFF); u8 hi=(u8)(v>>16);
        ml[r]=lo; mh[r]=hi;
        size_t ad = fragidx(gr+r, gc);
        bh2lo[ad]=lo; bh2hi[ad]=hi;
      }
      { // unconditional mirror; diagonal-straddle duplicates are identical exact ints
        size_t ad = fragidx(gc, gr);
        *(ushort4*)(bh2lo + ad) = *(ushort4*)ml;
        *(unsigned*)(bh2hi + ad) = (unsigned)mh[0] | ((unsigned)mh[1]<<8)
                                 | ((unsigned)mh[2]<<16) | ((unsigned)mh[3]<<24);
      }
    }
  }
}

// ---------------- K5b: bh2 diagonal leftovers — 16 blocks, 128x128, round-13 path ----------------
__global__ __launch_bounds__(256) void k_nn1d(const u8* __restrict__ bh1lo,
    const u8* __restrict__ bh1hi, const u8* __restrict__ b0f,
    u16* __restrict__ bh2lo, u8* __restrict__ bh2hi){
  int idx = blockIdx.x;
  idx = (idx&7)*2 + (idx>>3);               // bijective (16 = 8*2)
  const int bi = idx*2;                     // even rows carry the leftover diagonal tile
  const int r0=bi*128, c0=bi*128;
  const int t=threadIdx.x, w=t>>6, l=t&63;
  const int wr=(w>>1)*64, wc=(w&1)*64, fr=l&15, fg=l>>4;
  const i32x4 zer={0,0,0,0};
  i32x4 acc[4][4];
  #pragma unroll
  for(int i=0;i<4;i++)
    #pragma unroll
    for(int j=0;j<4;j++) acc[i][j]=zer;
  const size_t aoff = (size_t)fr*16 + (size_t)fg*256;
  const size_t gA = (size_t)((r0+wr)>>4)*GSTRIDE + aoff;
  const size_t gB = (size_t)((c0+wc)>>4)*GSTRIDE + aoff;
  for(int k0=0;k0<NP;k0+=64){
    const size_t kk=(size_t)k0*16;
    i32x4 ah[4], bf_[4];
    #pragma unroll
    for(int mi=0;mi<4;mi++) ah[mi]=*(const i32x4*)(bh1hi + gA + (size_t)mi*GSTRIDE + kk);
    #pragma unroll
    for(int nj=0;nj<4;nj++) bf_[nj]=*(const i32x4*)(b0f + gB + (size_t)nj*GSTRIDE + kk);
    #pragma unroll
    for(int mi=0;mi<4;mi++)
      #pragma unroll
      for(int nj=0;nj<4;nj++)
        acc[mi][nj]=__builtin_amdgcn_mfma_i32_16x16x64_i8(ah[mi],bf_[nj],acc[mi][nj],0,0,0);
  }
  #pragma unroll
  for(int mi=0;mi<4;mi++)
    #pragma unroll
    for(int nj=0;nj<4;nj++)
      #pragma unroll
      for(int r=0;r<4;r++) acc[mi][nj][r] <<= 7;
  for(int k0=0;k0<NP;k0+=64){
    const size_t kk=(size_t)k0*16;
    i32x4 al[4], bf_[4];
    #pragma unroll
    for(int mi=0;mi<4;mi++) al[mi]=*(const i32x4*)(bh1lo + gA + (size_t)mi*GSTRIDE + kk);
    #pragma unroll
    for(int nj=0;nj<4;nj++) bf_[nj]=*(const i32x4*)(b0f + gB + (size_t)nj*GSTRIDE + kk);
    #pragma unroll
    for(int mi=0;mi<4;mi++)
      #pragma unroll
      for(int nj=0;nj<4;nj++)
        acc[mi][nj]=__builtin_amdgcn_mfma_i32_16x16x64_i8(al[mi],bf_[nj],acc[mi][nj],0,0,0);
  }
  #pragma unroll
  for(int mi=0;mi<4;mi++){
    #pragma unroll
    for(int nj=0;nj<4;nj++){
      int gr=r0+wr+mi*16+fg*4, gc=c0+wc+nj*16+fr;
      #pragma unroll
      for(int r=0;r<4;r++){
        int v = acc[mi][nj][r];
        size_t ad = fragidx(gr+r, gc);
        bh2lo[ad]=(u16)(v & 0xFFFF); bh2hi[ad]=(u8)(v>>16);
      }
    }
  }
}

// ---------------- K6: fused flash-style softmax @ nodes (all frag-major inputs) ----------------
template<int H>
__device__ __forceinline__ void pv_body(const float* __restrict__ iw,
    const u8* __restrict__ bh1lo, const u8* __restrict__ bh1hi,
    const u16* __restrict__ bh2lo, const u8* __restrict__ bh2hi,
    const u16* __restrict__ ndT, const float* __restrict__ delta,
    float* __restrict__ traw, int rs,
    float (*Lm)[16], float (*Ls)[16], float (*Lacc)[16][4][64]){
  const int t = threadIdx.x, w = t>>6, l = t&63, fr = l&15, fg = l>>4;
  const int kbase = w*1024;                  // per-wave K quarter
  const float thr = b0_thr(delta[0]);
  const f32x4 zer={0.f,0.f,0.f,0.f};
  f32x4 acc[16];
  #pragma unroll
  for(int i=0;i<16;i++) acc[i]=zer;
  float m_run=-3.0e38f, s_run=0.f;
  const size_t af32 = ((size_t)rs*(NP>>4) + (size_t)(kbase>>4) + (fg>>1))*256
                    + (size_t)(fr*16 + (fg&1)*8);
  const float* ipf = iw + af32;
  const u16* p2lo = bh2lo + af32;
  const u8*  p2hi = bh2hi + af32;
  const u8* plo = bh1lo + af32;
  const u8* phi = bh1hi + af32;
  const size_t nb0 = (size_t)(kbase>>5)*512 + (size_t)(fr*32 + fg*8);
  for(int k0=0;k0<1024;k0+=32){
    const size_t idxf = (size_t)(k0>>4)*256;
    const size_t idxn = (size_t)k0*16;
    bf16x8 bfr[16];
    #pragma unroll
    for(int nj=0;nj<16;nj++)
      bfr[nj]=*(const bf16x8*)(ndT + (size_t)nj*65536 + nb0 + idxn);
    float vv[8];
    {
      float4 v0=*(const float4*)(ipf+idxf), v1=*(const float4*)(ipf+idxf+4);
      vv[0]=v0.x; vv[1]=v0.y; vv[2]=v0.z; vv[3]=v0.w;
      vv[4]=v1.x; vv[5]=v1.y; vv[6]=v1.z; vv[7]=v1.w;
    }
    float lg[8];
    if(H==0){
      #pragma unroll
      for(int e=0;e<8;e++) lg[e]=vv[e]>=thr?vv[e]:0.f;
    } else if(H==1){
      u64 llo=*(const u64*)(plo + idxf);
      u64 lhi=*(const u64*)(phi + idxf);
      #pragma unroll
      for(int e=0;e<8;e++){
        int bh_ = (int)((llo>>(8*e))&255u) | ((int)((lhi>>(8*e))&255u)<<7);
        lg[e]=(float)bh_*vv[e];
      }
    } else {
      u16x8 lv=*(const u16x8*)(p2lo + idxf);
      u64   hv=*(const u64*)(p2hi + idxf);
      #pragma unroll
      for(int e=0;e<8;e++){
        int v = (int)(unsigned short)lv[e] | ((int)((hv>>(8*e))&255u)<<16);
        lg[e]=(float)v*vv[e];
      }
    }
    float m_t = fmaxf(fmaxf(fmaxf(lg[0],lg[1]),fmaxf(lg[2],lg[3])),
                      fmaxf(fmaxf(lg[4],lg[5]),fmaxf(lg[6],lg[7])));
    m_t = fmaxf(m_t, __shfl_xor(m_t,16));
    m_t = fmaxf(m_t, __shfl_xor(m_t,32));
    if(__any(m_t > m_run + 6.0f)){
      float m_new = fmaxf(m_run, m_t);
      float sc = __expf(m_run - m_new);
      s_run *= sc;
      #pragma unroll
      for(int r=0;r<4;r++){
        float scr = __shfl(sc, fg*4+r);
        #pragma unroll
        for(int nj=0;nj<16;nj++) acc[nj][r]*=scr;
      }
      m_run = m_new;
    }
    bf16x8 af; float ss=0.f;
    #pragma unroll
    for(int e=0;e<8;e++){
      float p=__expf(lg[e]-m_run); ss+=p;
      af[e]=(short)f2bf(p);
    }
    s_run += ss;
    #pragma unroll
    for(int nj=0;nj<16;nj++)
      acc[nj]=__builtin_amdgcn_mfma_f32_16x16x32_bf16(af,bfr[nj],acc[nj],0,0,0);
  }
  s_run += __shfl_xor(s_run,16);
  s_run += __shfl_xor(s_run,32);
  if(fg==0) Lm[w][fr]=m_run;
  __syncthreads();
  float f_c[4];
  #pragma unroll
  for(int r=0;r<4;r++){
    int rr=fg*4+r;
    float ms=fmaxf(fmaxf(Lm[0][rr],Lm[1][rr]),fmaxf(Lm[2][rr],Lm[3][rr]));
    f_c[r]=__expf(Lm[w][rr]-ms);
  }
  {
    float ms=fmaxf(fmaxf(Lm[0][fr],Lm[1][fr]),fmaxf(Lm[2][fr],Lm[3][fr]));
    float fs=__expf(Lm[w][fr]-ms);
    if(fg==0) Ls[w][fr]=s_run*fs;
  }
  #pragma unroll
  for(int nj=0;nj<16;nj++)
    #pragma unroll
    for(int r=0;r<4;r++) acc[nj][r]*=f_c[r];
  if(w==1||w==3){
    int Ri=(w==1)?0:1;
    #pragma unroll
    for(int nj=0;nj<16;nj++)
      #pragma unroll
      for(int r=0;r<4;r++) Lacc[Ri][nj][r][l]=acc[nj][r];
  }
  __syncthreads();
  if(w==0||w==2){
    int Ri=(w==0)?0:1;
    #pragma unroll
    for(int nj=0;nj<16;nj++)
      #pragma unroll
      for(int r=0;r<4;r++) acc[nj][r]+=Lacc[Ri][nj][r][l];
  }
  __syncthreads();
  if(w==2){
    #pragma unroll
    for(int nj=0;nj<16;nj++)
      #pragma unroll
      for(int r=0;r<4;r++) Lacc[0][nj][r][l]=acc[nj][r];
  }
  __syncthreads();
  if(w==0){
    float sst[4];
    #pragma unroll
    for(int r=0;r<4;r++){
      int rr=fg*4+r;
      sst[r]=1.0f/(Ls[0][rr]+Ls[1][rr]+Ls[2][rr]+Ls[3][rr]);
    }
    #pragma unroll
    for(int nj=0;nj<16;nj++)
      #pragma unroll
      for(int r=0;r<4;r++){
        float v=(acc[nj][r]+Lacc[0][nj][r][l])*sst[r];
        traw[(size_t)(rs*16+fg*4+r)*ICH + nj*16+fr]=v;
      }
  }
}

// grid = 768 (1D): work-id -> rs = idx/3, hop = idx%3; XCD-chunked swizzle
__global__ __launch_bounds__(256) void k_pv3(const float* __restrict__ iw,
    const u8* __restrict__ bh1lo, const u8* __restrict__ bh1hi,
    const u16* __restrict__ bh2lo, const u8* __restrict__ bh2hi,
    const u16* __restrict__ ndT, const float* __restrict__ delta,
    float* __restrict__ trawcat){
  __shared__ float Lm[4][16], Ls[4][16];
  __shared__ float Lacc[2][16][4][64];
  int idx = blockIdx.x;
  idx = (idx&7)*96 + (idx>>3);              // bijective (768 = 8*96)
  const int rs = idx/3, h = idx - rs*3;
  float* traw = trawcat + (size_t)h*NP*ICH;
  if(h==0)      pv_body<0>(iw,bh1lo,bh1hi,bh2lo,bh2hi,ndT,delta,traw,rs,Lm,Ls,Lacc);
  else if(h==1) pv_body<1>(iw,bh1lo,bh1hi,bh2lo,bh2hi,ndT,delta,traw,rs,Lm,Ls,Lacc);
  else          pv_body<2>(iw,bh1lo,bh1hi,bh2lo,bh2hi,ndT,delta,traw,rs,Lm,Ls,Lacc);
}

// ---------------- prep: fold hop/fuse/bnf into res GEMM ----------------
__global__ __launch_bounds__(256) void k_prepA(const float* __restrict__ fw,
    const float* __restrict__ hw, const float* __restrict__ hb,
    const float* __restrict__ fb,
    const float* __restrict__ gf, const float* __restrict__ bef,
    const float* __restrict__ muf, const float* __restrict__ vaf,
    float* __restrict__ G, float* __restrict__ cf,
    float* __restrict__ sf, float* __restrict__ tf){
  const int t=threadIdx.x;
  if(blockIdx.x<768){
    int i=blockIdx.x>>8, oc=blockIdx.x&255;
    float s=0.f;
    const float* fr_=fw + (size_t)oc*768 + i*256;
    const float* hp=hw + (size_t)i*ICH*ICH + t;
    for(int j=0;j<256;j++) s=fmaf(fr_[j], hp[(size_t)j*ICH], s);
    G[((size_t)i*ICH + oc)*ICH + t]=s;
  } else {
    float iv=gf[t]*rsqrtf(vaf[t]+1e-5f);
    sf[t]=iv;
    tf[t]=bef[t]-muf[t]*iv;
    float s=fb[t];
    const float* fr_=fw + (size_t)t*768;
    for(int k=0;k<768;k++) s=fmaf(fr_[k], hb[k], s);
    cf[t]=s;
  }
}

__global__ __launch_bounds__(256) void k_prepB(const float* __restrict__ rw,
    const float* __restrict__ rb, const float* __restrict__ G,
    const float* __restrict__ cf, const float* __restrict__ sf,
    const float* __restrict__ tf, float* __restrict__ Wcat,
    float* __restrict__ evec){
  const int oc=blockIdx.x, t=threadIdx.x;
  __shared__ float rs_[256], rw2_[256];
  rw2_[t]=rw[(size_t)oc*512 + 256 + t];
  rs_[t]=rw2_[t]*sf[t];
  __syncthreads();
  Wcat[(size_t)oc*1024 + t] = rw[(size_t)oc*512 + t];
  #pragma unroll
  for(int i=0;i<3;i++){
    float s=0.f;
    const float* gp=G + (size_t)i*ICH*ICH + t;
    for(int m=0;m<256;m++) s=fmaf(rs_[m], gp[(size_t)m*ICH], s);
    Wcat[(size_t)oc*1024 + 256 + i*256 + t]=s;
  }
  if(t==0){
    float s=rb[oc];
    for(int m=0;m<256;m++) s=fmaf(rs_[m],cf[m],s)+rw2_[m]*tf[m];
    evec[oc]=s;
  }
}

// ---------------- tail: out = bnr( R0@x256 + Wcat_hops@trawcat + e ), transposed LDS ----------------
__global__ __launch_bounds__(256) void k_tail2(const float* __restrict__ trawcat,
    const float* __restrict__ Wcat, const float* __restrict__ evec,
    const float* __restrict__ xsrc,
    const float* __restrict__ g, const float* __restrict__ be,
    const float* __restrict__ mu, const float* __restrict__ va,
    float* __restrict__ Cout){
  const int n0=blockIdx.x*64, c0=blockIdx.y*64;
  __shared__ float asT[32][68], bsT[32][68];
  const int t=threadIdx.x, tx=t&15, ty=t>>4;
  float acc[4][4];
  #pragma unroll
  for(int i=0;i<4;i++)
    #pragma unroll
    for(int j=0;j<4;j++) acc[i][j]=0.f;
  for(int k0=0;k0<1024;k0+=32){
    __syncthreads();
    if(k0<256){
      int kk=t>>4, nv=(t&15)*4;
      #pragma unroll
      for(int k2=kk;k2<32;k2+=16)
        *(float4*)&asT[k2][nv] = *(const float4*)(xsrc + (size_t)(k0+k2)*NP + n0+nv);
    } else {
      int hop=(k0-256)>>8, kk0=(k0-256)&255;
      const float* A=trawcat + (size_t)hop*NP*ICH;
      int r=t>>3, kv=(t&7)*4;
      #pragma unroll
      for(int rr=r;rr<64;rr+=32){
        float4 v=*(const float4*)(A + (size_t)(n0+rr)*ICH + kk0+kv);
        asT[kv+0][rr]=v.x; asT[kv+1][rr]=v.y; asT[kv+2][rr]=v.z; asT[kv+3][rr]=v.w;
      }
    }
    {
      int r=t>>3, kv=(t&7)*4;
      #pragma unroll
      for(int rr=r;rr<64;rr+=32){
        float4 v=*(const float4*)(Wcat + (size_t)(c0+rr)*1024 + k0+kv);
        bsT[kv+0][rr]=v.x; bsT[kv+1][rr]=v.y; bsT[kv+2][rr]=v.z; bsT[kv+3][rr]=v.w;
      }
    }
    __syncthreads();
    #pragma unroll
    for(int k=0;k<32;k++){
      float4 av=*(const float4*)&asT[k][ty*4];
      float4 bv=*(const float4*)&bsT[k][tx*4];
      float avf[4]={av.x,av.y,av.z,av.w};
      float bvf[4]={bv.x,bv.y,bv.z,bv.w};
      #pragma unroll
      for(int i=0;i<4;i++)
        #pragma unroll
        for(int j=0;j<4;j++) acc[i][j]+=avf[i]*bvf[j];
    }
  }
  const int col=c0+tx*4, row=n0+ty*4;
  float sc[4], ad[4];
  #pragma unroll
  for(int j=0;j<4;j++){
    int c=col+j;
    float iv=g[c]*rsqrtf(va[c]+1e-5f);
    sc[j]=iv; ad[j]=be[c]-mu[c]*iv + evec[c]*iv;
  }
  #pragma unroll
  for(int j=0;j<4;j++){
    float4 ov;
    ov.x=acc[0][j]*sc[j]+ad[j]; ov.y=acc[1][j]*sc[j]+ad[j];
    ov.z=acc[2][j]*sc[j]+ad[j]; ov.w=acc[3][j]*sc[j]+ad[j];
    *(float4*)(Cout + (size_t)(col+j)*NP + row) = ov;
  }
}

__global__ void k_diag(float* out, int n, float val){
  int i = blockIdx.x*256 + threadIdx.x;
  if(i<n) out[i] = (i==0)? val : 0.f;
}

extern "C" void kernel_launch(void* const* d_in, const int* in_sizes, int n_in,
                              void* d_out, int out_size, void* d_ws, size_t ws_size,
                              hipStream_t stream){
  const float* x    =(const float*)d_in[0];
  const float* delta=(const float*)d_in[1];
  const float* w1w  =(const float*)d_in[2];
  const float* w1b  =(const float*)d_in[3];
  const float* g1   =(const float*)d_in[4];
  const float* be1  =(const float*)d_in[5];
  const float* mu1  =(const float*)d_in[6];
  const float* va1  =(const float*)d_in[7];
  const float* nw   =(const float*)d_in[8];
  const float* nb   =(const float*)d_in[9];
  const float* hw   =(const float*)d_in[10];
  const float* hb   =(const float*)d_in[11];
  const float* fw   =(const float*)d_in[12];
  const float* fb   =(const float*)d_in[13];
  const float* gf   =(const float*)d_in[14];
  const float* bef  =(const float*)d_in[15];
  const float* muf  =(const float*)d_in[16];
  const float* vaf  =(const float*)d_in[17];
  const float* rw   =(const float*)d_in[18];
  const float* rb   =(const float*)d_in[19];
  const float* gr   =(const float*)d_in[20];
  const float* ber  =(const float*)d_in[21];
  const float* mur  =(const float*)d_in[22];
  const float* var_ =(const float*)d_in[23];
  float* out=(float*)d_out;

  char* ws=(char*)d_ws;
  size_t o=0;
  auto alloc=[&](size_t bytes)->char*{ char* p=ws+o; o+=(bytes+255)&~(size_t)255; return p; };
  const size_t NN=(size_t)NP*NP;
  float* Wt    =(float*)alloc((size_t)BB*NP*ICH*4);   // 16.8 MB
  u16*   ndT   =(u16*)  alloc((size_t)BB*ICH*NP*2);   // 8.4 MB (frag-major)
  float* iw    =(float*)alloc(NN*4);                  // 67.1 MB (f32 frag)
  u8*    b0f   =(u8*)   alloc(NN);                    // 16.8 MB (u8 frag)
  u8*    bh1lo =(u8*)   alloc(NN);                    // 16.8 MB (u8 frag)
  u8*    bh1hi =(u8*)   alloc(NN);                    // 16.8 MB (u8 frag)
  u16*   bh2lo =(u16*)  alloc(NN*2);                  // 33.6 MB (u16 frag)
  u8*    bh2hi =(u8*)   alloc(NN);                    // 16.8 MB (u8 frag)
  float* trawc =(float*)alloc((size_t)3*NP*ICH*4);    // 12.6 MB
  float* G     =(float*)alloc((size_t)3*ICH*ICH*4);
  float* Wcat  =(float*)alloc((size_t)CINCH*1024*4);
  float* evec  =(float*)alloc(CINCH*4);
  float* cf    =(float*)alloc(ICH*4);
  float* sf    =(float*)alloc(ICH*4);
  float* tf    =(float*)alloc(ICH*4);
  if(o > ws_size){
    k_diag<<<dim3((out_size+255)/256),dim3(256),0,stream>>>(out, out_size, (float)ws_size);
    return;
  }
  dim3 blk(256);
  k_prepA<<<dim3(769),blk,0,stream>>>(fw,hw,hb,fb,gf,bef,muf,vaf,G,cf,sf,tf);
  k_prepB<<<dim3(512),blk,0,stream>>>(rw,rb,G,cf,sf,tf,Wcat,evec);
  k_proj<<<dim3(NP/64,ICH/64,BB),blk,0,stream>>>(x,w1w,w1b,g1,be1,mu1,va1,nw,nb,Wt,ndT);
  for(int b=0;b<BB;b++){
    const float* Wt_b  = Wt + (size_t)b*NP*ICH;
    const u16*   ndT_b = ndT + (size_t)b*ICH*NP;
    const float* x_b   = x + (size_t)b*CINCH*NP;
    float*       out_b = out + (size_t)b*CINCH*NP;
    k_iw  <<<dim3(2080),blk,0,stream>>>(Wt_b,iw,b0f,delta);
    k_nn0 <<<dim3(528),blk,0,stream>>>(b0f,bh1lo,bh1hi);
    k_nn1p<<<dim3(256),blk,0,stream>>>(bh1lo,bh1hi,b0f,bh2lo,bh2hi);
    k_nn1d<<<dim3(16),blk,0,stream>>>(bh1lo,bh1hi,b0f,bh2lo,bh2hi);
    k_pv3 <<<dim3(768),blk,0,stream>>>(iw,bh1lo,bh1hi,bh2lo,bh2hi,ndT_b,delta,trawc);
    k_tail2<<<dim3(64,8),blk,0,stream>>>(trawc,Wcat,evec,x_b,gr,ber,mur,var_,out_b);
  }
}

// Round 18
// 2275.460 us; speedup vs baseline: 1.0630x; 1.0615x over previous
//
#include <hip/hip_runtime.h>

#define CINCH 512
#define ICH 256
#define NP 4096
#define BB 4
#define GSTRIDE ((size_t)NP*16)   // 65536: bytes per 16-row fragment group (u8 frag)

typedef __attribute__((ext_vector_type(8))) short bf16x8;
typedef __attribute__((ext_vector_type(8))) unsigned short u16x8;
typedef __attribute__((ext_vector_type(4))) float f32x4;
typedef __attribute__((ext_vector_type(4))) int i32x4;
typedef unsigned short u16;
typedef unsigned char u8;
typedef unsigned long long u64;

__device__ __forceinline__ u16 f2bf(float f){
  unsigned u = __builtin_bit_cast(unsigned, f);
  u += 0x7FFFu + ((u>>16)&1u);
  return (u16)(u>>16);
}

__device__ __forceinline__ float b0_thr(float dv){
  if (dv <= 0.f) return -3.4e38f;
  if (dv >= 1.f) return  3.4e38f;
  return (float)log((double)dv/(1.0-(double)dv));
}

// u8 frag-major byte address: [row/16][k/16][row%16][k%16]
__device__ __forceinline__ size_t fragaddr(int row, int k){
  return (size_t)(row>>4)*GSTRIDE + (size_t)(k>>4)*256 + (size_t)((row&15)*16 + (k&15));
}
// generic frag-major ELEMENT offset: [row/16][col/16][row%16][col%16]
__device__ __forceinline__ size_t fragidx(int row, int col){
  return ((size_t)(row>>4)*(NP>>4) + (size_t)(col>>4))*256 + (size_t)((row&15)*16 + (col&15));
}
// ndT bf16 frag-major u16 offset: [ic/16][n/32][ic%16][(n>>3)&3][n&7]
__device__ __forceinline__ size_t ndfrag(int ic, int n){
  return ((size_t)(ic>>4)*(NP>>5) + (size_t)(n>>5))*512
       + (size_t)((ic&15)*32 + ((n>>3)&3)*8 + (n&7));
}

// ---------------- K1: wfeat (bn1, fp32-chunk + fp64 fold) + nodes frag-bf16 ----------------
__global__ __launch_bounds__(256) void k_proj(const float* __restrict__ x,
    const float* __restrict__ w1w, const float* __restrict__ w1b,
    const float* __restrict__ g1, const float* __restrict__ be1,
    const float* __restrict__ mu1, const float* __restrict__ va1,
    const float* __restrict__ nw, const float* __restrict__ nb,
    float* __restrict__ Wt, u16* __restrict__ ndT){
  const int b = blockIdx.z;
  const int n0 = blockIdx.x*64, c0 = blockIdx.y*64;
  const int t = threadIdx.x, tx=t&15, ty=t>>4;
  __shared__ float as_[32][68];
  __shared__ float w1T[32][68];
  __shared__ float w2T[32][68];
  double acc1d[4][4];
  float acc1[4][4], acc2[4][4];
  #pragma unroll
  for(int i=0;i<4;i++)
    #pragma unroll
    for(int j=0;j<4;j++){acc1d[i][j]=0.0; acc1[i][j]=0.f; acc2[i][j]=0.f;}
  const float* xb = x + (size_t)b*CINCH*NP;
  for(int cb=0; cb<CINCH; cb+=32){
    __syncthreads();
    #pragma unroll
    for(int h=0;h<2;h++){
      int f = t + h*256;
      {
        int row=f>>4, c4=f&15;
        float4 v=*(const float4*)(xb + (size_t)(cb+row)*NP + n0 + c4*4);
        *(float4*)&as_[row][c4*4] = v;
      }
      {
        int k=f&31, ocq=f>>5;
        float l1[4], l2[4];
        #pragma unroll
        for(int r=0;r<4;r++){
          l1[r]=w1w[(size_t)(c0+ocq*4+r)*CINCH + cb + k];
          l2[r]=nw [(size_t)(c0+ocq*4+r)*CINCH + cb + k];
        }
        *(float4*)&w1T[k][ocq*4] = *(float4*)l1;
        *(float4*)&w2T[k][ocq*4] = *(float4*)l2;
      }
    }
    __syncthreads();
    #pragma unroll
    for(int k=0;k<32;k++){
      float4 av=*(const float4*)&as_[k][ty*4];
      float4 b1=*(const float4*)&w1T[k][tx*4];
      float4 b2=*(const float4*)&w2T[k][tx*4];
      float avf[4]={av.x,av.y,av.z,av.w};
      float b1f[4]={b1.x,b1.y,b1.z,b1.w};
      float b2f[4]={b2.x,b2.y,b2.z,b2.w};
      #pragma unroll
      for(int i=0;i<4;i++)
        #pragma unroll
        for(int j=0;j<4;j++){
          acc1[i][j] = fmaf(avf[i], b1f[j], acc1[i][j]);
          acc2[i][j] = fmaf(avf[i], b2f[j], acc2[i][j]);
        }
    }
    #pragma unroll
    for(int i=0;i<4;i++)
      #pragma unroll
      for(int j=0;j<4;j++){ acc1d[i][j] += (double)acc1[i][j]; acc1[i][j]=0.f; }
  }
  float inv[4], add[4], b1v[4], b2v[4];
  #pragma unroll
  for(int j=0;j<4;j++){
    int c=c0+tx*4+j;
    inv[j]=g1[c]*rsqrtf(va1[c]+1e-5f);
    add[j]=be1[c]-mu1[c]*inv[j];
    b1v[j]=w1b[c]; b2v[j]=nb[c];
  }
  #pragma unroll
  for(int i=0;i<4;i++){
    int n=n0+ty*4+i;
    float4 ov;
    float o[4];
    #pragma unroll
    for(int j=0;j<4;j++) o[j]=((float)(acc1d[i][j]+(double)b1v[j]))*inv[j]+add[j];
    ov.x=o[0];ov.y=o[1];ov.z=o[2];ov.w=o[3];
    *(float4*)(Wt + ((size_t)b*NP + n)*ICH + c0+tx*4) = ov;
  }
  u16* ndTb = ndT + (size_t)b*ICH*NP;
  #pragma unroll
  for(int j=0;j<4;j++){
    int ic=c0+tx*4+j;
    ushort4 uv;
    uv.x=f2bf(acc2[0][j]+b2v[j]); uv.y=f2bf(acc2[1][j]+b2v[j]);
    uv.z=f2bf(acc2[2][j]+b2v[j]); uv.w=f2bf(acc2[3][j]+b2v[j]);
    *(ushort4*)(ndTb + ndfrag(ic, n0+ty*4)) = uv;
  }
}

// ---------------- K2: iw (f32 frag) = Wt Wt^T/16 (fp32-chunk + fp64 fold) + b0 ----------------
__global__ __launch_bounds__(256) void k_iw(const float* __restrict__ Wb,
    float* __restrict__ ob, u8* __restrict__ b0f, const float* __restrict__ delta){
  int tt = blockIdx.x;
  tt = (tt&7)*260 + (tt>>3);                // XCD-bijective (2080%8==0)
  int bi = (int)((sqrtf(8.f*(float)tt+1.f)-1.f)*0.5f);
  while(bi*(bi+1)/2 > tt) bi--;
  while((bi+1)*(bi+2)/2 <= tt) bi++;
  int bj = tt - bi*(bi+1)/2;
  const int r0=bi*64, c0=bj*64;
  const float thr = b0_thr(delta[0]);
  __shared__ float asT[32][68], bsT[32][68];
  const int t=threadIdx.x, tx=t&15, ty=t>>4;
  double accd[4][4];
  float accf[4][4];
  #pragma unroll
  for(int i=0;i<4;i++)
    #pragma unroll
    for(int j=0;j<4;j++){accd[i][j]=0.0; accf[i][j]=0.f;}
  for(int k0=0;k0<ICH;k0+=32){
    __syncthreads();
    {
      int r=t>>3, kv=(t&7)*4;
      #pragma unroll
      for(int rr=r; rr<64; rr+=32){
        float4 va=*(const float4*)(Wb + (size_t)(r0+rr)*ICH + k0+kv);
        asT[kv+0][rr]=va.x; asT[kv+1][rr]=va.y; asT[kv+2][rr]=va.z; asT[kv+3][rr]=va.w;
        float4 vb=*(const float4*)(Wb + (size_t)(c0+rr)*ICH + k0+kv);
        bsT[kv+0][rr]=vb.x; bsT[kv+1][rr]=vb.y; bsT[kv+2][rr]=vb.z; bsT[kv+3][rr]=vb.w;
      }
    }
    __syncthreads();
    #pragma unroll
    for(int k=0;k<32;k++){
      float4 av=*(const float4*)&asT[k][ty*4];
      float4 bv=*(const float4*)&bsT[k][tx*4];
      float avf[4]={av.x,av.y,av.z,av.w};
      float bvf[4]={bv.x,bv.y,bv.z,bv.w};
      #pragma unroll
      for(int i=0;i<4;i++)
        #pragma unroll
        for(int j=0;j<4;j++)
          accf[i][j] = fmaf(avf[i], bvf[j], accf[i][j]);
    }
    #pragma unroll
    for(int i=0;i<4;i++)
      #pragma unroll
      for(int j=0;j<4;j++){ accd[i][j] += (double)accf[i][j]; accf[i][j]=0.f; }
  }
  float vv[4][4];
  char bvs[4][4];
  #pragma unroll
  for(int i=0;i<4;i++)
    #pragma unroll
    for(int j=0;j<4;j++){
      float v = (float)(accd[i][j]*0.0625);
      vv[i][j]=v;
      bvs[i][j]= v>=thr ? 1 : 0;
    }
  #pragma unroll
  for(int i=0;i<4;i++){
    float4 ov; ov.x=vv[i][0];ov.y=vv[i][1];ov.z=vv[i][2];ov.w=vv[i][3];
    *(float4*)(ob + fragidx(r0+ty*4+i, c0+tx*4)) = ov;
    unsigned w = (u8)bvs[i][0] | ((u8)bvs[i][1]<<8) | ((u8)bvs[i][2]<<16) | ((u8)bvs[i][3]<<24);
    *(unsigned*)(b0f + fragaddr(r0+ty*4+i, c0+tx*4)) = w;
  }
  if(bi!=bj){
    #pragma unroll
    for(int j=0;j<4;j++){
      float4 ov; ov.x=vv[0][j];ov.y=vv[1][j];ov.z=vv[2][j];ov.w=vv[3][j];
      *(float4*)(ob + fragidx(c0+tx*4+j, r0+ty*4)) = ov;
      unsigned w = (u8)bvs[0][j] | ((u8)bvs[1][j]<<8) | ((u8)bvs[2][j]<<16) | ((u8)bvs[3][j]<<24);
      *(unsigned*)(b0f + fragaddr(c0+tx*4+j, r0+ty*4)) = w;
    }
  }
}

// ---------------- K4: bh1 = b0 @ b0 (i8 MFMA, triangular, frag-layout in/out) ----------------
__global__ __launch_bounds__(256) void k_nn0(const u8* __restrict__ b0f,
    u8* __restrict__ bh1lo, u8* __restrict__ bh1hi){
  int tt = blockIdx.x;
  tt = (tt&7)*66 + (tt>>3);                 // XCD-bijective (528%8==0)
  int bi = (int)((sqrtf(8.f*(float)tt+1.f)-1.f)*0.5f);
  while(bi*(bi+1)/2 > tt) bi--;
  while((bi+1)*(bi+2)/2 <= tt) bi++;
  int bj = tt - bi*(bi+1)/2;
  const int r0=bi*128, c0=bj*128;
  const int t=threadIdx.x, w=t>>6, l=t&63;
  const int wr=(w>>1)*64, wc=(w&1)*64, fr=l&15, fg=l>>4;
  const i32x4 zer={0,0,0,0};
  i32x4 acc[4][4];
  #pragma unroll
  for(int i=0;i<4;i++)
    #pragma unroll
    for(int j=0;j<4;j++) acc[i][j]=zer;
  const size_t aoff = (size_t)fr*16 + (size_t)fg*256;
  const u8* pA[4]; const u8* pB[4];
  #pragma unroll
  for(int mi=0;mi<4;mi++) pA[mi]=b0f + (size_t)(((r0+wr)>>4) + mi)*GSTRIDE + aoff;
  #pragma unroll
  for(int nj=0;nj<4;nj++) pB[nj]=b0f + (size_t)(((c0+wc)>>4) + nj)*GSTRIDE + aoff;
  for(int k0=0;k0<NP;k0+=64){
    const size_t idx=(size_t)k0*16;
    i32x4 af[4], bf_[4];
    #pragma unroll
    for(int mi=0;mi<4;mi++) af[mi]=*(const i32x4*)(pA[mi]+idx);
    #pragma unroll
    for(int nj=0;nj<4;nj++) bf_[nj]=*(const i32x4*)(pB[nj]+idx);
    #pragma unroll
    for(int mi=0;mi<4;mi++)
      #pragma unroll
      for(int nj=0;nj<4;nj++)
        acc[mi][nj]=__builtin_amdgcn_mfma_i32_16x16x64_i8(af[mi],bf_[nj],acc[mi][nj],0,0,0);
  }
  #pragma unroll
  for(int mi=0;mi<4;mi++){
    #pragma unroll
    for(int nj=0;nj<4;nj++){
      int gc=c0+wc+nj*16+fr;
      int grb=r0+wr+mi*16+fg*4;
      u8 lob[4], hib[4];
      #pragma unroll
      for(int r=0;r<4;r++){
        int v=acc[mi][nj][r];
        lob[r]=(u8)(v&127); hib[r]=(u8)(v>>7);
        size_t ad=fragaddr(grb+r,gc);
        bh1lo[ad]=lob[r];
        bh1hi[ad]=hib[r];
      }
      if(bi!=bj){
        unsigned wlo = (unsigned)lob[0] | ((unsigned)lob[1]<<8) | ((unsigned)lob[2]<<16) | ((unsigned)lob[3]<<24);
        unsigned whi = (unsigned)hib[0] | ((unsigned)hib[1]<<8) | ((unsigned)hib[2]<<16) | ((unsigned)hib[3]<<24);
        size_t ad=fragaddr(gc,grb);
        *(unsigned*)(bh1lo+ad)=wlo;
        *(unsigned*)(bh1hi+ad)=whi;
      }
    }
  }
}

// ---------------- K5: bh2 (u16 lo + u8 hi frag) = bh1 @ b0 ----------------
// Single accumulator: hi-sweep, acc <<= 7, lo-sweep (exact, <=2^24)
__global__ __launch_bounds__(256) void k_nn1(const u8* __restrict__ bh1lo,
    const u8* __restrict__ bh1hi, const u8* __restrict__ b0f,
    u16* __restrict__ bh2lo, u8* __restrict__ bh2hi){
  int tt = blockIdx.x;
  tt = (tt&7)*66 + (tt>>3);                 // XCD-bijective (528%8==0)
  int bi = (int)((sqrtf(8.f*(float)tt+1.f)-1.f)*0.5f);
  while(bi*(bi+1)/2 > tt) bi--;
  while((bi+1)*(bi+2)/2 <= tt) bi++;
  int bj = tt - bi*(bi+1)/2;
  const int r0=bi*128, c0=bj*128;
  const int t=threadIdx.x, w=t>>6, l=t&63;
  const int wr=(w>>1)*64, wc=(w&1)*64, fr=l&15, fg=l>>4;
  const i32x4 zer={0,0,0,0};
  i32x4 acc[4][4];
  #pragma unroll
  for(int i=0;i<4;i++)
    #pragma unroll
    for(int j=0;j<4;j++) acc[i][j]=zer;
  const size_t aoff = (size_t)fr*16 + (size_t)fg*256;
  const u8* pAlo[4]; const u8* pAhi[4]; const u8* pB[4];
  #pragma unroll
  for(int mi=0;mi<4;mi++){
    size_t g = (size_t)(((r0+wr)>>4) + mi)*GSTRIDE + aoff;
    pAlo[mi]=bh1lo+g; pAhi[mi]=bh1hi+g;
  }
  #pragma unroll
  for(int nj=0;nj<4;nj++)
    pB[nj]=b0f + (size_t)(((c0+wc)>>4) + nj)*GSTRIDE + aoff;
  // hi sweep
  for(int k0=0;k0<NP;k0+=64){
    const size_t idx=(size_t)k0*16;
    i32x4 ah[4], bf_[4];
    #pragma unroll
    for(int mi=0;mi<4;mi++) ah[mi]=*(const i32x4*)(pAhi[mi]+idx);
    #pragma unroll
    for(int nj=0;nj<4;nj++) bf_[nj]=*(const i32x4*)(pB[nj]+idx);
    #pragma unroll
    for(int mi=0;mi<4;mi++)
      #pragma unroll
      for(int nj=0;nj<4;nj++)
        acc[mi][nj]=__builtin_amdgcn_mfma_i32_16x16x64_i8(ah[mi],bf_[nj],acc[mi][nj],0,0,0);
  }
  // scale by 128 in-register
  #pragma unroll
  for(int mi=0;mi<4;mi++)
    #pragma unroll
    for(int nj=0;nj<4;nj++)
      #pragma unroll
      for(int r=0;r<4;r++) acc[mi][nj][r] <<= 7;
  // lo sweep (accumulates into same acc)
  for(int k0=0;k0<NP;k0+=64){
    const size_t idx=(size_t)k0*16;
    i32x4 al[4], bf_[4];
    #pragma unroll
    for(int mi=0;mi<4;mi++) al[mi]=*(const i32x4*)(pAlo[mi]+idx);
    #pragma unroll
    for(int nj=0;nj<4;nj++) bf_[nj]=*(const i32x4*)(pB[nj]+idx);
    #pragma unroll
    for(int mi=0;mi<4;mi++)
      #pragma unroll
      for(int nj=0;nj<4;nj++)
        acc[mi][nj]=__builtin_amdgcn_mfma_i32_16x16x64_i8(al[mi],bf_[nj],acc[mi][nj],0,0,0);
  }
  #pragma unroll
  for(int mi=0;mi<4;mi++){
    #pragma unroll
    for(int nj=0;nj<4;nj++){
      int gr=r0+wr+mi*16+fg*4, gc=c0+wc+nj*16+fr;
      u16 ml[4]; u8 mh[4];
      #pragma unroll
      for(int r=0;r<4;r++){
        int v = acc[mi][nj][r];
        u16 lo=(u16)(v & 0xFFFF); u8 hi=(u8)(v>>16);
        ml[r]=lo; mh[r]=hi;
        size_t ad = fragidx(gr+r, gc);
        bh2lo[ad]=lo; bh2hi[ad]=hi;
      }
      if(bi!=bj){
        size_t ad = fragidx(gc, gr);
        *(ushort4*)(bh2lo + ad) = *(ushort4*)ml;
        *(unsigned*)(bh2hi + ad) = (unsigned)mh[0] | ((unsigned)mh[1]<<8)
                                 | ((unsigned)mh[2]<<16) | ((unsigned)mh[3]<<24);
      }
    }
  }
}

// ---------------- K6: fused flash-style softmax @ nodes (all frag-major inputs) ----------------
template<int H>
__device__ __forceinline__ void pv_body(const float* __restrict__ iw,
    const u8* __restrict__ bh1lo, const u8* __restrict__ bh1hi,
    const u16* __restrict__ bh2lo, const u8* __restrict__ bh2hi,
    const u16* __restrict__ ndT, const float* __restrict__ delta,
    float* __restrict__ traw, int rs,
    float (*Lm)[16], float (*Ls)[16], float (*Lacc)[16][4][64]){
  const int t = threadIdx.x, w = t>>6, l = t&63, fr = l&15, fg = l>>4;
  const int kbase = w*1024;                  // per-wave K quarter
  const float thr = b0_thr(delta[0]);
  const f32x4 zer={0.f,0.f,0.f,0.f};
  f32x4 acc[16];
  #pragma unroll
  for(int i=0;i<16;i++) acc[i]=zer;
  float m_run=-3.0e38f, s_run=0.f;
  const size_t af32 = ((size_t)rs*(NP>>4) + (size_t)(kbase>>4) + (fg>>1))*256
                    + (size_t)(fr*16 + (fg&1)*8);
  const float* ipf = iw + af32;
  const u16* p2lo = bh2lo + af32;
  const u8*  p2hi = bh2hi + af32;
  const u8* plo = bh1lo + af32;
  const u8* phi = bh1hi + af32;
  const size_t nb0 = (size_t)(kbase>>5)*512 + (size_t)(fr*32 + fg*8);
  for(int k0=0;k0<1024;k0+=32){
    const size_t idxf = (size_t)(k0>>4)*256;
    const size_t idxn = (size_t)k0*16;
    bf16x8 bfr[16];
    #pragma unroll
    for(int nj=0;nj<16;nj++)
      bfr[nj]=*(const bf16x8*)(ndT + (size_t)nj*65536 + nb0 + idxn);
    float vv[8];
    {
      float4 v0=*(const float4*)(ipf+idxf), v1=*(const float4*)(ipf+idxf+4);
      vv[0]=v0.x; vv[1]=v0.y; vv[2]=v0.z; vv[3]=v0.w;
      vv[4]=v1.x; vv[5]=v1.y; vv[6]=v1.z; vv[7]=v1.w;
    }
    float lg[8];
    if(H==0){
      #pragma unroll
      for(int e=0;e<8;e++) lg[e]=vv[e]>=thr?vv[e]:0.f;
    } else if(H==1){
      u64 llo=*(const u64*)(plo + idxf);
      u64 lhi=*(const u64*)(phi + idxf);
      #pragma unroll
      for(int e=0;e<8;e++){
        int bh_ = (int)((llo>>(8*e))&255u) | ((int)((lhi>>(8*e))&255u)<<7);
        lg[e]=(float)bh_*vv[e];
      }
    } else {
      u16x8 lv=*(const u16x8*)(p2lo + idxf);
      u64   hv=*(const u64*)(p2hi + idxf);
      #pragma unroll
      for(int e=0;e<8;e++){
        int v = (int)(unsigned short)lv[e] | ((int)((hv>>(8*e))&255u)<<16);
        lg[e]=(float)v*vv[e];
      }
    }
    float m_t = fmaxf(fmaxf(fmaxf(lg[0],lg[1]),fmaxf(lg[2],lg[3])),
                      fmaxf(fmaxf(lg[4],lg[5]),fmaxf(lg[6],lg[7])));
    m_t = fmaxf(m_t, __shfl_xor(m_t,16));
    m_t = fmaxf(m_t, __shfl_xor(m_t,32));
    if(__any(m_t > m_run + 6.0f)){
      float m_new = fmaxf(m_run, m_t);
      float sc = __expf(m_run - m_new);
      s_run *= sc;
      #pragma unroll
      for(int r=0;r<4;r++){
        float scr = __shfl(sc, fg*4+r);
        #pragma unroll
        for(int nj=0;nj<16;nj++) acc[nj][r]*=scr;
      }
      m_run = m_new;
    }
    bf16x8 af; float ss=0.f;
    #pragma unroll
    for(int e=0;e<8;e++){
      float p=__expf(lg[e]-m_run); ss+=p;
      af[e]=(short)f2bf(p);
    }
    s_run += ss;
    #pragma unroll
    for(int nj=0;nj<16;nj++)
      acc[nj]=__builtin_amdgcn_mfma_f32_16x16x32_bf16(af,bfr[nj],acc[nj],0,0,0);
  }
  s_run += __shfl_xor(s_run,16);
  s_run += __shfl_xor(s_run,32);
  if(fg==0) Lm[w][fr]=m_run;
  __syncthreads();
  float f_c[4];
  #pragma unroll
  for(int r=0;r<4;r++){
    int rr=fg*4+r;
    float ms=fmaxf(fmaxf(Lm[0][rr],Lm[1][rr]),fmaxf(Lm[2][rr],Lm[3][rr]));
    f_c[r]=__expf(Lm[w][rr]-ms);
  }
  {
    float ms=fmaxf(fmaxf(Lm[0][fr],Lm[1][fr]),fmaxf(Lm[2][fr],Lm[3][fr]));
    float fs=__expf(Lm[w][fr]-ms);
    if(fg==0) Ls[w][fr]=s_run*fs;
  }
  #pragma unroll
  for(int nj=0;nj<16;nj++)
    #pragma unroll
    for(int r=0;r<4;r++) acc[nj][r]*=f_c[r];
  if(w==1||w==3){
    int Ri=(w==1)?0:1;
    #pragma unroll
    for(int nj=0;nj<16;nj++)
      #pragma unroll
      for(int r=0;r<4;r++) Lacc[Ri][nj][r][l]=acc[nj][r];
  }
  __syncthreads();
  if(w==0||w==2){
    int Ri=(w==0)?0:1;
    #pragma unroll
    for(int nj=0;nj<16;nj++)
      #pragma unroll
      for(int r=0;r<4;r++) acc[nj][r]+=Lacc[Ri][nj][r][l];
  }
  __syncthreads();
  if(w==2){
    #pragma unroll
    for(int nj=0;nj<16;nj++)
      #pragma unroll
      for(int r=0;r<4;r++) Lacc[0][nj][r][l]=acc[nj][r];
  }
  __syncthreads();
  if(w==0){
    float sst[4];
    #pragma unroll
    for(int r=0;r<4;r++){
      int rr=fg*4+r;
      sst[r]=1.0f/(Ls[0][rr]+Ls[1][rr]+Ls[2][rr]+Ls[3][rr]);
    }
    #pragma unroll
    for(int nj=0;nj<16;nj++)
      #pragma unroll
      for(int r=0;r<4;r++){
        float v=(acc[nj][r]+Lacc[0][nj][r][l])*sst[r];
        traw[(size_t)(rs*16+fg*4+r)*ICH + nj*16+fr]=v;
      }
  }
}

// grid = 768 (1D): work-id -> rs = idx/3, hop = idx%3; XCD-chunked swizzle
__global__ __launch_bounds__(256) void k_pv3(const float* __restrict__ iw,
    const u8* __restrict__ bh1lo, const u8* __restrict__ bh1hi,
    const u16* __restrict__ bh2lo, const u8* __restrict__ bh2hi,
    const u16* __restrict__ ndT, const float* __restrict__ delta,
    float* __restrict__ trawcat){
  __shared__ float Lm[4][16], Ls[4][16];
  __shared__ float Lacc[2][16][4][64];
  int idx = blockIdx.x;
  idx = (idx&7)*96 + (idx>>3);              // bijective (768 = 8*96)
  const int rs = idx/3, h = idx - rs*3;
  float* traw = trawcat + (size_t)h*NP*ICH;
  if(h==0)      pv_body<0>(iw,bh1lo,bh1hi,bh2lo,bh2hi,ndT,delta,traw,rs,Lm,Ls,Lacc);
  else if(h==1) pv_body<1>(iw,bh1lo,bh1hi,bh2lo,bh2hi,ndT,delta,traw,rs,Lm,Ls,Lacc);
  else          pv_body<2>(iw,bh1lo,bh1hi,bh2lo,bh2hi,ndT,delta,traw,rs,Lm,Ls,Lacc);
}

// ---------------- prep: fold hop/fuse/bnf into res GEMM ----------------
__global__ __launch_bounds__(256) void k_prepA(const float* __restrict__ fw,
    const float* __restrict__ hw, const float* __restrict__ hb,
    const float* __restrict__ fb,
    const float* __restrict__ gf, const float* __restrict__ bef,
    const float* __restrict__ muf, const float* __restrict__ vaf,
    float* __restrict__ G, float* __restrict__ cf,
    float* __restrict__ sf, float* __restrict__ tf){
  const int t=threadIdx.x;
  if(blockIdx.x<768){
    int i=blockIdx.x>>8, oc=blockIdx.x&255;
    float s=0.f;
    const float* fr_=fw + (size_t)oc*768 + i*256;
    const float* hp=hw + (size_t)i*ICH*ICH + t;
    for(int j=0;j<256;j++) s=fmaf(fr_[j], hp[(size_t)j*ICH], s);
    G[((size_t)i*ICH + oc)*ICH + t]=s;
  } else {
    float iv=gf[t]*rsqrtf(vaf[t]+1e-5f);
    sf[t]=iv;
    tf[t]=bef[t]-muf[t]*iv;
    float s=fb[t];
    const float* fr_=fw + (size_t)t*768;
    for(int k=0;k<768;k++) s=fmaf(fr_[k], hb[k], s);
    cf[t]=s;
  }
}

__global__ __launch_bounds__(256) void k_prepB(const float* __restrict__ rw,
    const float* __restrict__ rb, const float* __restrict__ G,
    const float* __restrict__ cf, const float* __restrict__ sf,
    const float* __restrict__ tf, float* __restrict__ Wcat,
    float* __restrict__ evec){
  const int oc=blockIdx.x, t=threadIdx.x;
  __shared__ float rs_[256], rw2_[256];
  rw2_[t]=rw[(size_t)oc*512 + 256 + t];
  rs_[t]=rw2_[t]*sf[t];
  __syncthreads();
  Wcat[(size_t)oc*1024 + t] = rw[(size_t)oc*512 + t];
  #pragma unroll
  for(int i=0;i<3;i++){
    float s=0.f;
    const float* gp=G + (size_t)i*ICH*ICH + t;
    for(int m=0;m<256;m++) s=fmaf(rs_[m], gp[(size_t)m*ICH], s);
    Wcat[(size_t)oc*1024 + 256 + i*256 + t]=s;
  }
  if(t==0){
    float s=rb[oc];
    for(int m=0;m<256;m++) s=fmaf(rs_[m],cf[m],s)+rw2_[m]*tf[m];
    evec[oc]=s;
  }
}

// ---------------- tail: out = bnr( R0@x256 + Wcat_hops@trawcat + e ), transposed LDS ----------------
__global__ __launch_bounds__(256) void k_tail2(const float* __restrict__ trawcat,
    const float* __restrict__ Wcat, const float* __restrict__ evec,
    const float* __restrict__ xsrc,
    const float* __restrict__ g, const float* __restrict__ be,
    const float* __restrict__ mu, const float* __restrict__ va,
    float* __restrict__ Cout){
  const int n0=blockIdx.x*64, c0=blockIdx.y*64;
  __shared__ float asT[32][68], bsT[32][68];
  const int t=threadIdx.x, tx=t&15, ty=t>>4;
  float acc[4][4];
  #pragma unroll
  for(int i=0;i<4;i++)
    #pragma unroll
    for(int j=0;j<4;j++) acc[i][j]=0.f;
  for(int k0=0;k0<1024;k0+=32){
    __syncthreads();
    if(k0<256){
      int kk=t>>4, nv=(t&15)*4;
      #pragma unroll
      for(int k2=kk;k2<32;k2+=16)
        *(float4*)&asT[k2][nv] = *(const float4*)(xsrc + (size_t)(k0+k2)*NP + n0+nv);
    } else {
      int hop=(k0-256)>>8, kk0=(k0-256)&255;
      const float* A=trawcat + (size_t)hop*NP*ICH;
      int r=t>>3, kv=(t&7)*4;
      #pragma unroll
      for(int rr=r;rr<64;rr+=32){
        float4 v=*(const float4*)(A + (size_t)(n0+rr)*ICH + kk0+kv);
        asT[kv+0][rr]=v.x; asT[kv+1][rr]=v.y; asT[kv+2][rr]=v.z; asT[kv+3][rr]=v.w;
      }
    }
    {
      int r=t>>3, kv=(t&7)*4;
      #pragma unroll
      for(int rr=r;rr<64;rr+=32){
        float4 v=*(const float4*)(Wcat + (size_t)(c0+rr)*1024 + k0+kv);
        bsT[kv+0][rr]=v.x; bsT[kv+1][rr]=v.y; bsT[kv+2][rr]=v.z; bsT[kv+3][rr]=v.w;
      }
    }
    __syncthreads();
    #pragma unroll
    for(int k=0;k<32;k++){
      float4 av=*(const float4*)&asT[k][ty*4];
      float4 bv=*(const float4*)&bsT[k][tx*4];
      float avf[4]={av.x,av.y,av.z,av.w};
      float bvf[4]={bv.x,bv.y,bv.z,bv.w};
      #pragma unroll
      for(int i=0;i<4;i++)
        #pragma unroll
        for(int j=0;j<4;j++) acc[i][j]+=avf[i]*bvf[j];
    }
  }
  const int col=c0+tx*4, row=n0+ty*4;
  float sc[4], ad[4];
  #pragma unroll
  for(int j=0;j<4;j++){
    int c=col+j;
    float iv=g[c]*rsqrtf(va[c]+1e-5f);
    sc[j]=iv; ad[j]=be[c]-mu[c]*iv + evec[c]*iv;
  }
  #pragma unroll
  for(int j=0;j<4;j++){
    float4 ov;
    ov.x=acc[0][j]*sc[j]+ad[j]; ov.y=acc[1][j]*sc[j]+ad[j];
    ov.z=acc[2][j]*sc[j]+ad[j]; ov.w=acc[3][j]*sc[j]+ad[j];
    *(float4*)(Cout + (size_t)(col+j)*NP + row) = ov;
  }
}

__global__ void k_diag(float* out, int n, float val){
  int i = blockIdx.x*256 + threadIdx.x;
  if(i<n) out[i] = (i==0)? val : 0.f;
}

extern "C" void kernel_launch(void* const* d_in, const int* in_sizes, int n_in,
                              void* d_out, int out_size, void* d_ws, size_t ws_size,
                              hipStream_t stream){
  const float* x    =(const float*)d_in[0];
  const float* delta=(const float*)d_in[1];
  const float* w1w  =(const float*)d_in[2];
  const float* w1b  =(const float*)d_in[3];
  const float* g1   =(const float*)d_in[4];
  const float* be1  =(const float*)d_in[5];
  const float* mu1  =(const float*)d_in[6];
  const float* va1  =(const float*)d_in[7];
  const float* nw   =(const float*)d_in[8];
  const float* nb   =(const float*)d_in[9];
  const float* hw   =(const float*)d_in[10];
  const float* hb   =(const float*)d_in[11];
  const float* fw   =(const float*)d_in[12];
  const float* fb   =(const float*)d_in[13];
  const float* gf   =(const float*)d_in[14];
  const float* bef  =(const float*)d_in[15];
  const float* muf  =(const float*)d_in[16];
  const float* vaf  =(const float*)d_in[17];
  const float* rw   =(const float*)d_in[18];
  const float* rb   =(const float*)d_in[19];
  const float* gr   =(const float*)d_in[20];
  const float* ber  =(const float*)d_in[21];
  const float* mur  =(const float*)d_in[22];
  const float* var_ =(const float*)d_in[23];
  float* out=(float*)d_out;

  char* ws=(char*)d_ws;
  size_t o=0;
  auto alloc=[&](size_t bytes)->char*{ char* p=ws+o; o+=(bytes+255)&~(size_t)255; return p; };
  const size_t NN=(size_t)NP*NP;
  float* Wt    =(float*)alloc((size_t)BB*NP*ICH*4);   // 16.8 MB
  u16*   ndT   =(u16*)  alloc((size_t)BB*ICH*NP*2);   // 8.4 MB (frag-major)
  float* iw    =(float*)alloc(NN*4);                  // 67.1 MB (f32 frag)
  u8*    b0f   =(u8*)   alloc(NN);                    // 16.8 MB (u8 frag)
  u8*    bh1lo =(u8*)   alloc(NN);                    // 16.8 MB (u8 frag)
  u8*    bh1hi =(u8*)   alloc(NN);                    // 16.8 MB (u8 frag)
  u16*   bh2lo =(u16*)  alloc(NN*2);                  // 33.6 MB (u16 frag)
  u8*    bh2hi =(u8*)   alloc(NN);                    // 16.8 MB (u8 frag)
  float* trawc =(float*)alloc((size_t)3*NP*ICH*4);    // 12.6 MB
  float* G     =(float*)alloc((size_t)3*ICH*ICH*4);
  float* Wcat  =(float*)alloc((size_t)CINCH*1024*4);
  float* evec  =(float*)alloc(CINCH*4);
  float* cf    =(float*)alloc(ICH*4);
  float* sf    =(float*)alloc(ICH*4);
  float* tf    =(float*)alloc(ICH*4);
  if(o > ws_size){
    k_diag<<<dim3((out_size+255)/256),dim3(256),0,stream>>>(out, out_size, (float)ws_size);
    return;
  }
  dim3 blk(256);
  k_prepA<<<dim3(769),blk,0,stream>>>(fw,hw,hb,fb,gf,bef,muf,vaf,G,cf,sf,tf);
  k_prepB<<<dim3(512),blk,0,stream>>>(rw,rb,G,cf,sf,tf,Wcat,evec);
  k_proj<<<dim3(NP/64,ICH/64,BB),blk,0,stream>>>(x,w1w,w1b,g1,be1,mu1,va1,nw,nb,Wt,ndT);
  for(int b=0;b<BB;b++){
    const float* Wt_b  = Wt + (size_t)b*NP*ICH;
    const u16*   ndT_b = ndT + (size_t)b*ICH*NP;
    const float* x_b   = x + (size_t)b*CINCH*NP;
    float*       out_b = out + (size_t)b*CINCH*NP;
    k_iw  <<<dim3(2080),blk,0,stream>>>(Wt_b,iw,b0f,delta);
    k_nn0 <<<dim3(528),blk,0,stream>>>(b0f,bh1lo,bh1hi);
    k_nn1 <<<dim3(528),blk,0,stream>>>(bh1lo,bh1hi,b0f,bh2lo,bh2hi);
    k_pv3 <<<dim3(768),blk,0,stream>>>(iw,bh1lo,bh1hi,bh2lo,bh2hi,ndT_b,delta,trawc);
    k_tail2<<<dim3(64,8),blk,0,stream>>>(trawc,Wcat,evec,x_b,gr,ber,mur,var_,out_b);
  }
}